// Round 4
// baseline (167.354 us; speedup 1.0000x reference)
//
#include <hip/hip_runtime.h>
#include <hip/hip_bf16.h>

typedef unsigned short u16;
typedef unsigned int u32;
typedef short bf16x8 __attribute__((ext_vector_type(8)));
typedef float f32x4 __attribute__((ext_vector_type(4)));

#define N_TOK 4096
#define C_DIM 256
#define HEADS 8
#define HD 32
#define SCALE_F 0.17677669529663687f   /* 32^-0.5 */

__device__ inline u16 f2bf(float f) {
    u32 u = __float_as_uint(f);
    u += 0x7fffu + ((u >> 16) & 1u);
    return (u16)(u >> 16);
}

__device__ inline void gload16(const void* g, void* l) {
    __builtin_amdgcn_global_load_lds((const __attribute__((address_space(1))) u32*)g,
                                     (__attribute__((address_space(3))) u32*)l, 16, 0, 0);
}

// ---------------- weight fp32 -> bf16 ----------------
__global__ __launch_bounds__(256) void conv_w(const float* __restrict__ w1, const float* __restrict__ w2,
                                              u16* __restrict__ o1, u16* __restrict__ o2) {
    int i = blockIdx.x * 256 + threadIdx.x;
    if (i < 1024 * 256) o1[i] = f2bf(w1[i]);
    if (i < 256 * 256)  o2[i] = f2bf(w2[i]);
}

// ---------------- sin/cos [4096][32] -> [32][4096] ----------------
__global__ __launch_bounds__(256) void transpose_sc(const float* __restrict__ s, const float* __restrict__ c,
                                                    float* __restrict__ sT, float* __restrict__ cT) {
    int l0 = blockIdx.x * 64;
    const float* src = blockIdx.y ? c : s;
    float* dst = blockIdx.y ? cT : sT;
    __shared__ float tl[64][33];
    int t = threadIdx.x;
    int d = t & 31, r = t >> 5;
#pragma unroll
    for (int i = 0; i < 8; ++i) tl[r + i * 8][d] = src[(size_t)(l0 + r + i * 8) * HD + d];
    __syncthreads();
    int li = t & 63, dr = t >> 6;
#pragma unroll
    for (int i = 0; i < 8; ++i) dst[(size_t)(dr + i * 4) * N_TOK + l0 + li] = tl[li][dr + i * 4];
}

// ---------------- x[b][c][l] fp32 -> xT[b][l][c] bf16 ----------------
__global__ __launch_bounds__(256) void transpose_x(const float* __restrict__ x, u16* __restrict__ xT) {
    int b = blockIdx.z;
    int c0 = blockIdx.y * 32, l0 = blockIdx.x * 32;
    const float* xb = x + ((size_t)b * C_DIM + c0) * N_TOK + l0;
    __shared__ u16 tl[32][33];
    int t = threadIdx.x;
    int li = t & 31, ci = t >> 5;
#pragma unroll
    for (int i = 0; i < 4; ++i)
        tl[ci + i * 8][li] = f2bf(xb[(size_t)(ci + i * 8) * N_TOK + li]);
    __syncthreads();
    int c2 = t & 15, lr = t >> 4;
    u16* outp = xT + ((size_t)b * N_TOK + l0) * C_DIM + c0;
#pragma unroll
    for (int i = 0; i < 2; ++i) {
        int l = lr + i * 16;
        u32 pv = (u32)tl[2 * c2][l] | ((u32)tl[2 * c2 + 1][l] << 16);
        *(u32*)(outp + (size_t)l * C_DIM + 2 * c2) = pv;
    }
}

// ---------------- bf16 MFMA GEMM, BK=64, XOR slot swizzle (conflict-free reads) ----------------
// C[b][m][l] = sum_k A[m][k]*B[b][l][k] + bias[m]
// LDS linear [row][slot0..7] of 16B slots; LDS(row,t) holds global slot t^(row&7).
__global__ __launch_bounds__(256) void gemm_bt(const u16* __restrict__ A, const u16* __restrict__ Bm,
                                               const float* __restrict__ bias, float* __restrict__ C,
                                               int M, int L, int K) {
    int bt = blockIdx.z;
    int m0 = blockIdx.y * 128;
    int l0 = blockIdx.x * 128;
    const u16* Bb = Bm + (size_t)bt * L * K;
    float* Cb = C + (size_t)bt * M * L;

    __shared__ u16 As[128 * 64];
    __shared__ u16 Bs[128 * 64];

    int t = threadIdx.x;
    int w = t >> 6, lane = t & 63;
    int wr = (w >> 1) * 64, wc = (w & 1) * 64;
    int fr = lane & 15, kg = lane >> 4;

    f32x4 acc[4][4] = {};

    for (int k0 = 0; k0 < K; k0 += 64) {
#pragma unroll
        for (int j = 0; j < 4; ++j) {
            int c = j * 256 + w * 64 + lane;
            int row = c >> 3, slot = c & 7;
            int gslot = slot ^ (row & 7);
            u16* abase = (u16*)As + (size_t)(j * 256 + w * 64) * 8;
            u16* bbase = (u16*)Bs + (size_t)(j * 256 + w * 64) * 8;
            gload16(A + (size_t)(m0 + row) * K + k0 + gslot * 8, abase);
            gload16(Bb + (size_t)(l0 + row) * K + k0 + gslot * 8, bbase);
        }
        __syncthreads();
#pragma unroll
        for (int kk = 0; kk < 2; ++kk) {
            bf16x8 af[4], bfr[4];
#pragma unroll
            for (int i = 0; i < 4; ++i) {
                int ra = wr + i * 16 + fr;
                int rb = wc + i * 16 + fr;
                af[i]  = *(const bf16x8*)(As + (size_t)ra * 64 + (size_t)((kk * 4 + kg) ^ (ra & 7)) * 8);
                bfr[i] = *(const bf16x8*)(Bs + (size_t)rb * 64 + (size_t)((kk * 4 + kg) ^ (rb & 7)) * 8);
            }
#pragma unroll
            for (int i = 0; i < 4; ++i)
#pragma unroll
                for (int jj = 0; jj < 4; ++jj)
                    acc[i][jj] = __builtin_amdgcn_mfma_f32_16x16x32_bf16(af[i], bfr[jj], acc[i][jj], 0, 0, 0);
        }
        __syncthreads();
    }

    int rg = (lane >> 4) * 4;
#pragma unroll
    for (int i = 0; i < 4; ++i)
#pragma unroll
        for (int jj = 0; jj < 4; ++jj) {
            int col = l0 + wc + jj * 16 + fr;
#pragma unroll
            for (int r = 0; r < 4; ++r) {
                int row = m0 + wr + i * 16 + rg + r;
                Cb[(size_t)row * L + col] = acc[i][jj][r] + bias[row];
            }
        }
}

// ---------------- lepe: depthwise 5x5, pad 2, on v channels of qkvo -> bf16 ----------------
__global__ __launch_bounds__(256) void lepe_conv(const float* __restrict__ qkvo, const float* __restrict__ wl,
                                                 const float* __restrict__ bl, u16* __restrict__ lepe) {
    int ht = blockIdx.x, c = blockIdx.y, b = blockIdx.z;
    const float* src = qkvo + ((size_t)b * 1024 + 512 + c) * N_TOK;
    u16* dst = lepe + ((size_t)b * C_DIM + c) * N_TOK;
    __shared__ float tile[20][72];
    __shared__ float wcoef[25];
    int t = threadIdx.x;
    if (t < 25) wcoef[t] = wl[c * 25 + t];
    int h0 = ht * 16;
    for (int i = t; i < 20 * 72; i += 256) {
        int r = i / 72, cc = i % 72;
        int gh = h0 + r - 2, gw = cc - 4;
        float v = 0.f;
        if (gh >= 0 && gh < 64 && gw >= 0 && gw < 64) v = src[gh * 64 + gw];
        tile[r][cc] = v;
    }
    __syncthreads();
    int wq = t & 15, hh = t >> 4;
    int w0 = wq * 4;
    float bb = bl[c];
    float acc[4] = {bb, bb, bb, bb};
#pragma unroll
    for (int i = 0; i < 5; ++i) {
        const float* rowp = &tile[hh + i][0];
        float4 a0 = *(const float4*)(rowp + w0);
        float4 a1 = *(const float4*)(rowp + w0 + 4);
        float4 a2 = *(const float4*)(rowp + w0 + 8);
        float f[12] = {a0.x, a0.y, a0.z, a0.w, a1.x, a1.y, a1.z, a1.w, a2.x, a2.y, a2.z, a2.w};
#pragma unroll
        for (int jj = 0; jj < 5; ++jj) {
            float wv_ = wcoef[i * 5 + jj];
#pragma unroll
            for (int ow = 0; ow < 4; ++ow)
                acc[ow] += f[ow + jj + 2] * wv_;
        }
    }
    int h = h0 + hh;
    uint2 pv;
    pv.x = (u32)f2bf(acc[0]) | ((u32)f2bf(acc[1]) << 16);
    pv.y = (u32)f2bf(acc[2]) | ((u32)f2bf(acc[3]) << 16);
    *(uint2*)(dst + h * 64 + w0) = pv;
}

// ---------------- kv reduction via MFMA ----------------
// Per (chunk of 512 tokens, bn): stage elu+theta(k), v as bf16 [32][128+pad] tiles,
// each wave MFMAs its 32-token slice; block-reduce partials; ksum/vsum in fp32.
__global__ __launch_bounds__(256) void kv_reduce(const float* __restrict__ qkvo, const float* __restrict__ sinT,
                                                 const float* __restrict__ cosT, float* __restrict__ part_kv,
                                                 float* __restrict__ part_ks, float* __restrict__ part_vs) {
    int chunk = blockIdx.x, bn = blockIdx.y;
    int b = bn >> 3, n = bn & 7;
    const float* kp = qkvo + ((size_t)b * 1024 + 256 + n * HD) * N_TOK;
    const float* vp = qkvo + ((size_t)b * 1024 + 512 + n * HD) * N_TOK;
    int lbase = chunk * 512;

    __shared__ u16 ks_bf[32][136];
    __shared__ u16 v_bf[32][136];
    __shared__ float red[4096];

    int t = threadIdx.x;
    int w = t >> 6, lane = t & 63;
    int h = t >> 7;            // 0/1
    int lcol = t & 127;
    int fr = lane & 15, kg = lane >> 4;

    f32x4 acc[2][2] = {};
    float ksum_p[16] = {};     // idx 2i+jj -> row 4i+2h+jj
    float vsum_p[16] = {};     // idx i -> row 2i+h

    for (int st = 0; st < 4; ++st) {
        int token = lbase + st * 128 + lcol;
        __syncthreads();
        // stage k pairs: elu+1, accumulate pre-theta sums, theta-shift, pack bf16
#pragma unroll
        for (int i = 0; i < 8; ++i) {
            int pr = 2 * i + h;
            int d0 = 2 * pr, d1 = 2 * pr + 1;
            float k0 = kp[(size_t)d0 * N_TOK + token];
            float k1 = kp[(size_t)d1 * N_TOK + token];
            float e0 = k0 > 0.f ? k0 + 1.f : __expf(k0);
            float e1 = k1 > 0.f ? k1 + 1.f : __expf(k1);
            ksum_p[2 * i]     += e0;
            ksum_p[2 * i + 1] += e1;
            float se = sinT[(size_t)d0 * N_TOK + token];
            float so = sinT[(size_t)d1 * N_TOK + token];
            float ce = cosT[(size_t)d0 * N_TOK + token];
            float co = cosT[(size_t)d1 * N_TOK + token];
            ks_bf[d0][lcol] = f2bf(e0 * ce - e1 * se);
            ks_bf[d1][lcol] = f2bf(e1 * co + e0 * so);
        }
        // stage v
#pragma unroll
        for (int i = 0; i < 16; ++i) {
            int d = 2 * i + h;
            float vv = vp[(size_t)d * N_TOK + token];
            vsum_p[i] += vv;
            v_bf[d][lcol] = f2bf(vv);
        }
        __syncthreads();
        // MFMA: wave w covers staged tokens [w*32, w*32+32)
        int kcol = w * 32 + kg * 8;
        bf16x8 af[2], bfv[2];
#pragma unroll
        for (int i = 0; i < 2; ++i) {
            af[i]  = *(const bf16x8*)&ks_bf[i * 16 + fr][kcol];
            bfv[i] = *(const bf16x8*)&v_bf[i * 16 + fr][kcol];
        }
#pragma unroll
        for (int i = 0; i < 2; ++i)
#pragma unroll
            for (int jj = 0; jj < 2; ++jj)
                acc[i][jj] = __builtin_amdgcn_mfma_f32_16x16x32_bf16(af[i], bfv[jj], acc[i][jj], 0, 0, 0);
    }
    // ---- ksum reduce ----
    __syncthreads();
#pragma unroll
    for (int i = 0; i < 8; ++i) {
        red[(4 * i + 2 * h + 0) * 128 + lcol] = ksum_p[2 * i];
        red[(4 * i + 2 * h + 1) * 128 + lcol] = ksum_p[2 * i + 1];
    }
    __syncthreads();
    if (t < 32) {
        float s = 0;
        for (int l = 0; l < 128; ++l) s += red[t * 128 + l];
        part_ks[((size_t)bn * 8 + chunk) * 32 + t] = s;
    }
    __syncthreads();
    // ---- vsum reduce ----
#pragma unroll
    for (int i = 0; i < 16; ++i)
        red[(2 * i + h) * 128 + lcol] = vsum_p[i];
    __syncthreads();
    if (t < 32) {
        float s = 0;
        for (int l = 0; l < 128; ++l) s += red[t * 128 + l];
        part_vs[((size_t)bn * 8 + chunk) * 32 + t] = s;
    }
    __syncthreads();
    // ---- kv partial: per-wave C frags -> block reduce ----
#pragma unroll
    for (int i = 0; i < 2; ++i)
#pragma unroll
        for (int jj = 0; jj < 2; ++jj)
#pragma unroll
            for (int r = 0; r < 4; ++r) {
                int row = i * 16 + kg * 4 + r;
                int col = jj * 16 + fr;
                red[w * 1024 + row * 32 + col] = acc[i][jj][r];
            }
    __syncthreads();
    float* pkv = part_kv + ((size_t)bn * 8 + chunk) * 1024;
#pragma unroll
    for (int i = 0; i < 4; ++i) {
        int el = i * 256 + t;
        pkv[el] = red[el] + red[1024 + el] + red[2048 + el] + red[3072 + el];
    }
}

// kv_final: sum 8 chunk partials -> kvT bf16 [e][d]; kmean/vmean
__global__ __launch_bounds__(256) void kv_final(const float* __restrict__ part_kv, const float* __restrict__ part_ks,
                                                const float* __restrict__ part_vs, u16* __restrict__ kvT_bf,
                                                float* __restrict__ kmean, float* __restrict__ vmean) {
    int bn = blockIdx.x;
    int t = threadIdx.x;
    const float* p = part_kv + (size_t)bn * 8 * 1024;
    const float s2c = SCALE_F / (float)N_TOK;
#pragma unroll
    for (int i = 0; i < 4; ++i) {
        int sl = t + i * 256;          // sl = d*32 + e
        float s = 0;
#pragma unroll
        for (int c = 0; c < 8; ++c) s += p[(size_t)c * 1024 + sl];
        float val = s * s2c;
        int d = sl >> 5, e = sl & 31;
        kvT_bf[(size_t)bn * 1024 + e * 32 + d] = f2bf(val);
    }
    if (t < 32) {
        float s = 0, sv = 0;
        for (int c = 0; c < 8; ++c) {
            s  += part_ks[((size_t)bn * 8 + c) * 32 + t];
            sv += part_vs[((size_t)bn * 8 + c) * 32 + t];
        }
        kmean[bn * 32 + t] = s * (1.f / (float)N_TOK);
        vmean[bn * 32 + t] = sv * (1.f / (float)N_TOK);
    }
}

// ---------------- attention epilogue, MFMA matvec -> resnT[b][l][c] bf16 ----------------
__global__ __launch_bounds__(256) void attn_epilogue(const float* __restrict__ qkvo, const float* __restrict__ sinT,
                                                     const float* __restrict__ cosT, const u16* __restrict__ kvT_bf,
                                                     const float* __restrict__ kmean, const float* __restrict__ vmean,
                                                     const u16* __restrict__ lepe, u16* __restrict__ resnT) {
    int lt = blockIdx.x, bn = blockIdx.y;
    int b = bn >> 3, n = bn & 7;
    const float* qp = qkvo + ((size_t)b * 1024 + n * HD) * N_TOK;
    const float* op = qkvo + ((size_t)b * 1024 + 768 + n * HD) * N_TOK;
    const u16* lp = lepe + ((size_t)b * C_DIM + n * HD) * N_TOK;

    __shared__ u16 kvb[32 * 40];            // kv^T [e][d] bf16, stride 40
    __shared__ float kml[32], vml[32];
    __shared__ u16 Atile[4][64 * 40];       // per-wave q' bf16 [tok][d], stride 40
    __shared__ float Rtile[4][64 * 36];     // per-wave res f32 [tok][e], stride 36

    int t = threadIdx.x;
    int w = t >> 6, lane = t & 63;

    if (t < 128) {
        int e = t >> 2, d0 = (t & 3) * 8;
        *(uint4*)(kvb + e * 40 + d0) = *(const uint4*)(kvT_bf + (size_t)bn * 1024 + e * 32 + d0);
    }
    if (t < 32) { kml[t] = kmean[bn * 32 + t]; vml[t] = vmean[bn * 32 + t]; }
    __syncthreads();

    int token = lt * 256 + w * 64 + lane;

    float qv[32];
    float z = 0.f;
#pragma unroll
    for (int d = 0; d < 32; ++d) {
        float x_ = qp[(size_t)d * N_TOK + token];
        float e_ = x_ > 0.f ? x_ + 1.f : __expf(x_);
        qv[d] = e_;
        z += e_ * kml[d];
    }
    z *= SCALE_F;
#pragma unroll
    for (int p = 0; p < 16; ++p) {
        float se = sinT[(size_t)(2 * p) * N_TOK + token];
        float so = sinT[(size_t)(2 * p + 1) * N_TOK + token];
        float ce = cosT[(size_t)(2 * p) * N_TOK + token];
        float co = cosT[(size_t)(2 * p + 1) * N_TOK + token];
        float a = qv[2 * p], bb = qv[2 * p + 1];
        qv[2 * p]     = a * ce - bb * se;
        qv[2 * p + 1] = bb * co + a * so;
    }
    float mult = 1.f + 1.f / (z + 1e-6f);

    u16* Aw = Atile[w];
#pragma unroll
    for (int j4 = 0; j4 < 4; ++j4) {
        uint4 u;
        u.x = (u32)f2bf(qv[8 * j4 + 0]) | ((u32)f2bf(qv[8 * j4 + 1]) << 16);
        u.y = (u32)f2bf(qv[8 * j4 + 2]) | ((u32)f2bf(qv[8 * j4 + 3]) << 16);
        u.z = (u32)f2bf(qv[8 * j4 + 4]) | ((u32)f2bf(qv[8 * j4 + 5]) << 16);
        u.w = (u32)f2bf(qv[8 * j4 + 6]) | ((u32)f2bf(qv[8 * j4 + 7]) << 16);
        *(uint4*)(Aw + lane * 40 + j4 * 8) = u;
    }
    __syncthreads();

    int fr = lane & 15, kg = lane >> 4;
    bf16x8 af[4], bfr[2];
#pragma unroll
    for (int i = 0; i < 4; ++i)
        af[i] = *(const bf16x8*)(Aw + (i * 16 + fr) * 40 + kg * 8);
#pragma unroll
    for (int jj = 0; jj < 2; ++jj)
        bfr[jj] = *(const bf16x8*)(kvb + (jj * 16 + fr) * 40 + kg * 8);

    float* Rw = Rtile[w];
    f32x4 zero = {0.f, 0.f, 0.f, 0.f};
#pragma unroll
    for (int i = 0; i < 4; ++i)
#pragma unroll
        for (int jj = 0; jj < 2; ++jj) {
            f32x4 acc = __builtin_amdgcn_mfma_f32_16x16x32_bf16(af[i], bfr[jj], zero, 0, 0, 0);
#pragma unroll
            for (int r = 0; r < 4; ++r)
                Rw[(i * 16 + kg * 4 + r) * 36 + jj * 16 + fr] = acc[r];
        }
    __syncthreads();

    float res[32];
#pragma unroll
    for (int j = 0; j < 8; ++j) {
        f32x4 vr = *(const f32x4*)(Rw + lane * 36 + j * 4);
        res[4 * j] = vr[0]; res[4 * j + 1] = vr[1]; res[4 * j + 2] = vr[2]; res[4 * j + 3] = vr[3];
    }

    u16* dst0 = resnT + ((size_t)b * N_TOK + token) * C_DIM + n * HD;
#pragma unroll
    for (int g = 0; g < 4; ++g) {
        float vv[8];
#pragma unroll
        for (int e2 = 0; e2 < 8; ++e2) {
            int ee = g * 8 + e2;
            float lx = __uint_as_float((u32)lp[(size_t)ee * N_TOK + token] << 16);
            float ov = op[(size_t)ee * N_TOK + token];
            float rx = res[ee] * mult - z * vml[ee];
            vv[e2] = (rx + lx) * ov;
        }
        uint4 u;
        u.x = (u32)f2bf(vv[0]) | ((u32)f2bf(vv[1]) << 16);
        u.y = (u32)f2bf(vv[2]) | ((u32)f2bf(vv[3]) << 16);
        u.z = (u32)f2bf(vv[4]) | ((u32)f2bf(vv[5]) << 16);
        u.w = (u32)f2bf(vv[6]) | ((u32)f2bf(vv[7]) << 16);
        ((uint4*)(dst0 + g * 8))[0] = u;
    }
}

extern "C" void kernel_launch(void* const* d_in, const int* in_sizes, int n_in,
                              void* d_out, int out_size, void* d_ws, size_t ws_size,
                              hipStream_t stream) {
    const float* x      = (const float*)d_in[0];
    const float* sinp   = (const float*)d_in[1];
    const float* cosp   = (const float*)d_in[2];
    const float* w_qkvo = (const float*)d_in[3];
    const float* b_qkvo = (const float*)d_in[4];
    const float* w_lepe = (const float*)d_in[5];
    const float* b_lepe = (const float*)d_in[6];
    const float* w_proj = (const float*)d_in[7];
    const float* b_proj = (const float*)d_in[8];

    char* ws = (char*)d_ws;
    size_t off = 0;
    auto alloc = [&](size_t bytes) { size_t o = off; off = (off + bytes + 255) & ~(size_t)255; return o; };
    u16*   wbf     = (u16*)(ws + alloc((size_t)1024 * 256 * 2));
    u16*   wpbf    = (u16*)(ws + alloc((size_t)256 * 256 * 2));
    u16*   xT      = (u16*)(ws + alloc((size_t)8 * 4096 * 256 * 2));
    float* qkvo    = (float*)(ws + alloc((size_t)8 * 1024 * 4096 * 4));
    u16*   lepe    = (u16*)(ws + alloc((size_t)8 * 256 * 4096 * 2));
    u16*   resnT   = (u16*)(ws + alloc((size_t)8 * 4096 * 256 * 2));
    float* part_kv = (float*)(ws + alloc((size_t)64 * 8 * 1024 * 4));
    float* part_ks = (float*)(ws + alloc((size_t)64 * 8 * 32 * 4));
    float* part_vs = (float*)(ws + alloc((size_t)64 * 8 * 32 * 4));
    u16*   kvT_bf  = (u16*)(ws + alloc((size_t)64 * 1024 * 2));
    float* kmean   = (float*)(ws + alloc((size_t)64 * 32 * 4));
    float* vmean   = (float*)(ws + alloc((size_t)64 * 32 * 4));
    float* sinT    = (float*)(ws + alloc((size_t)32 * 4096 * 4));
    float* cosT    = (float*)(ws + alloc((size_t)32 * 4096 * 4));
    if (off > ws_size) return;  // insufficient workspace -> loud validation failure

    conv_w<<<dim3(1024), dim3(256), 0, stream>>>(w_qkvo, w_proj, wbf, wpbf);
    transpose_sc<<<dim3(64, 2), dim3(256), 0, stream>>>(sinp, cosp, sinT, cosT);
    transpose_x<<<dim3(128, 8, 8), dim3(256), 0, stream>>>(x, xT);
    gemm_bt<<<dim3(32, 8, 8), dim3(256), 0, stream>>>(wbf, xT, b_qkvo, qkvo, 1024, 4096, 256);
    lepe_conv<<<dim3(4, 256, 8), dim3(256), 0, stream>>>(qkvo, w_lepe, b_lepe, lepe);
    kv_reduce<<<dim3(8, 64), dim3(256), 0, stream>>>(qkvo, sinT, cosT, part_kv, part_ks, part_vs);
    kv_final<<<dim3(64), dim3(256), 0, stream>>>(part_kv, part_ks, part_vs, kvT_bf, kmean, vmean);
    attn_epilogue<<<dim3(16, 64), dim3(256), 0, stream>>>(qkvo, sinT, cosT, kvT_bf, kmean, vmean, lepe, resnT);
    gemm_bt<<<dim3(32, 2, 8), dim3(256), 0, stream>>>(wpbf, resnT, b_proj, (float*)d_out, 256, 4096, 256);
}

// Round 5
// 128.004 us; speedup vs baseline: 1.3074x; 1.3074x over previous
//
#include <hip/hip_runtime.h>
#include <hip/hip_bf16.h>

typedef unsigned short u16;
typedef unsigned int u32;
typedef short bf16x8 __attribute__((ext_vector_type(8)));
typedef float f32x4 __attribute__((ext_vector_type(4)));
typedef u32 u32x4 __attribute__((ext_vector_type(4)));

#define N_TOK 4096
#define C_DIM 256
#define HEADS 8
#define HD 32
#define SCALE_F 0.17677669529663687f   /* 32^-0.5 */

__device__ inline u16 f2bf(float f) {
    u32 u = __float_as_uint(f);
    u += 0x7fffu + ((u >> 16) & 1u);
    return (u16)(u >> 16);
}
__device__ inline float bf_lo(u32 u) { return __uint_as_float(u << 16); }
__device__ inline float bf_hi(u32 u) { return __uint_as_float(u & 0xffff0000u); }

__device__ inline void gload16(const void* g, void* l) {
    __builtin_amdgcn_global_load_lds((const __attribute__((address_space(1))) u32*)g,
                                     (__attribute__((address_space(3))) u32*)l, 16, 0, 0);
}

// ---------------- weight fp32 -> bf16 ----------------
__global__ __launch_bounds__(256) void conv_w(const float* __restrict__ w1, const float* __restrict__ w2,
                                              u16* __restrict__ o1, u16* __restrict__ o2) {
    int i = blockIdx.x * 256 + threadIdx.x;
    if (i < 1024 * 256) o1[i] = f2bf(w1[i]);
    if (i < 256 * 256)  o2[i] = f2bf(w2[i]);
}

// ---------------- sin/cos [4096][32] -> packed bf16x2 scT[32][4096] (lo=sin, hi=cos) ----------------
__global__ __launch_bounds__(256) void make_sc(const float* __restrict__ s, const float* __restrict__ c,
                                               u32* __restrict__ scT) {
    int l0 = blockIdx.x * 64;
    __shared__ float ts[64][33];
    __shared__ float tc[64][33];
    int t = threadIdx.x;
    int d = t & 31, r = t >> 5;
#pragma unroll
    for (int i = 0; i < 8; ++i) {
        ts[r + i * 8][d] = s[(size_t)(l0 + r + i * 8) * HD + d];
        tc[r + i * 8][d] = c[(size_t)(l0 + r + i * 8) * HD + d];
    }
    __syncthreads();
    int li = t & 63, dr = t >> 6;
#pragma unroll
    for (int i = 0; i < 8; ++i) {
        int dd = dr * 8 + i;
        scT[(size_t)dd * N_TOK + l0 + li] = (u32)f2bf(ts[li][dd]) | ((u32)f2bf(tc[li][dd]) << 16);
    }
}

// ---------------- x[b][c][l] fp32 -> xT[b][l][c] bf16 ----------------
__global__ __launch_bounds__(256) void transpose_x(const float* __restrict__ x, u16* __restrict__ xT) {
    int b = blockIdx.z;
    int c0 = blockIdx.y * 32, l0 = blockIdx.x * 32;
    const float* xb = x + ((size_t)b * C_DIM + c0) * N_TOK + l0;
    __shared__ u16 tl[32][33];
    int t = threadIdx.x;
    int li = t & 31, ci = t >> 5;
#pragma unroll
    for (int i = 0; i < 4; ++i)
        tl[ci + i * 8][li] = f2bf(xb[(size_t)(ci + i * 8) * N_TOK + li]);
    __syncthreads();
    int c2 = t & 15, lr = t >> 4;
    u16* outp = xT + ((size_t)b * N_TOK + l0) * C_DIM + c0;
#pragma unroll
    for (int i = 0; i < 2; ++i) {
        int l = lr + i * 16;
        u32 pv = (u32)tl[2 * c2][l] | ((u32)tl[2 * c2 + 1][l] << 16);
        *(u32*)(outp + (size_t)l * C_DIM + 2 * c2) = pv;
    }
}

// ---------------- bf16 MFMA GEMM, BK=64, XOR slot swizzle ----------------
__global__ __launch_bounds__(256) void gemm_bt(const u16* __restrict__ A, const u16* __restrict__ Bm,
                                               const float* __restrict__ bias, float* __restrict__ C,
                                               int M, int L, int K) {
    int bt = blockIdx.z;
    int m0 = blockIdx.y * 128;
    int l0 = blockIdx.x * 128;
    const u16* Bb = Bm + (size_t)bt * L * K;
    float* Cb = C + (size_t)bt * M * L;

    __shared__ u16 As[128 * 64];
    __shared__ u16 Bs[128 * 64];

    int t = threadIdx.x;
    int w = t >> 6, lane = t & 63;
    int wr = (w >> 1) * 64, wc = (w & 1) * 64;
    int fr = lane & 15, kg = lane >> 4;

    f32x4 acc[4][4] = {};

    for (int k0 = 0; k0 < K; k0 += 64) {
#pragma unroll
        for (int j = 0; j < 4; ++j) {
            int c = j * 256 + w * 64 + lane;
            int row = c >> 3, slot = c & 7;
            int gslot = slot ^ (row & 7);
            u16* abase = (u16*)As + (size_t)(j * 256 + w * 64) * 8;
            u16* bbase = (u16*)Bs + (size_t)(j * 256 + w * 64) * 8;
            gload16(A + (size_t)(m0 + row) * K + k0 + gslot * 8, abase);
            gload16(Bb + (size_t)(l0 + row) * K + k0 + gslot * 8, bbase);
        }
        __syncthreads();
#pragma unroll
        for (int kk = 0; kk < 2; ++kk) {
            bf16x8 af[4], bfr[4];
#pragma unroll
            for (int i = 0; i < 4; ++i) {
                int ra = wr + i * 16 + fr;
                int rb = wc + i * 16 + fr;
                af[i]  = *(const bf16x8*)(As + (size_t)ra * 64 + (size_t)((kk * 4 + kg) ^ (ra & 7)) * 8);
                bfr[i] = *(const bf16x8*)(Bs + (size_t)rb * 64 + (size_t)((kk * 4 + kg) ^ (rb & 7)) * 8);
            }
#pragma unroll
            for (int i = 0; i < 4; ++i)
#pragma unroll
                for (int jj = 0; jj < 4; ++jj)
                    acc[i][jj] = __builtin_amdgcn_mfma_f32_16x16x32_bf16(af[i], bfr[jj], acc[i][jj], 0, 0, 0);
        }
        __syncthreads();
    }

    int rg = (lane >> 4) * 4;
#pragma unroll
    for (int i = 0; i < 4; ++i)
#pragma unroll
        for (int jj = 0; jj < 4; ++jj) {
            int col = l0 + wc + jj * 16 + fr;
#pragma unroll
            for (int r = 0; r < 4; ++r) {
                int row = m0 + wr + i * 16 + rg + r;
                Cb[(size_t)row * L + col] = acc[i][jj][r] + bias[row];
            }
        }
}

// ---------------- lepe: depthwise 5x5, pad 2, on v channels of qkvo -> bf16 ----------------
__global__ __launch_bounds__(256) void lepe_conv(const float* __restrict__ qkvo, const float* __restrict__ wl,
                                                 const float* __restrict__ bl, u16* __restrict__ lepe) {
    int ht = blockIdx.x, c = blockIdx.y, b = blockIdx.z;
    const float* src = qkvo + ((size_t)b * 1024 + 512 + c) * N_TOK;
    u16* dst = lepe + ((size_t)b * C_DIM + c) * N_TOK;
    __shared__ float tile[20][72];
    __shared__ float wcoef[25];
    int t = threadIdx.x;
    if (t < 25) wcoef[t] = wl[c * 25 + t];
    int h0 = ht * 16;
    for (int i = t; i < 20 * 72; i += 256) {
        int r = i / 72, cc = i % 72;
        int gh = h0 + r - 2, gw = cc - 4;
        float v = 0.f;
        if (gh >= 0 && gh < 64 && gw >= 0 && gw < 64) v = src[gh * 64 + gw];
        tile[r][cc] = v;
    }
    __syncthreads();
    int wq = t & 15, hh = t >> 4;
    int w0 = wq * 4;
    float bb = bl[c];
    float acc[4] = {bb, bb, bb, bb};
#pragma unroll
    for (int i = 0; i < 5; ++i) {
        const float* rowp = &tile[hh + i][0];
        float4 a0 = *(const float4*)(rowp + w0);
        float4 a1 = *(const float4*)(rowp + w0 + 4);
        float4 a2 = *(const float4*)(rowp + w0 + 8);
        float f[12] = {a0.x, a0.y, a0.z, a0.w, a1.x, a1.y, a1.z, a1.w, a2.x, a2.y, a2.z, a2.w};
#pragma unroll
        for (int jj = 0; jj < 5; ++jj) {
            float wv_ = wcoef[i * 5 + jj];
#pragma unroll
            for (int ow = 0; ow < 4; ++ow)
                acc[ow] += f[ow + jj + 2] * wv_;
        }
    }
    int h = h0 + hh;
    uint2 pv;
    pv.x = (u32)f2bf(acc[0]) | ((u32)f2bf(acc[1]) << 16);
    pv.y = (u32)f2bf(acc[2]) | ((u32)f2bf(acc[3]) << 16);
    *(uint2*)(dst + h * 64 + w0) = pv;
}

// ---------------- kv reduction via MFMA, batched vector staging ----------------
// 16 chunks x 64 bn; 256 tokens/block, 2 stages of 128.
__global__ __launch_bounds__(256) void kv_reduce(const float* __restrict__ qkvo, const u32* __restrict__ scT,
                                                 float* __restrict__ part_kv, float* __restrict__ part_ks,
                                                 float* __restrict__ part_vs) {
    int chunk = blockIdx.x, bn = blockIdx.y;
    int b = bn >> 3, n = bn & 7;
    const float* kp = qkvo + ((size_t)b * 1024 + 256 + n * HD) * N_TOK;
    const float* vp = qkvo + ((size_t)b * 1024 + 512 + n * HD) * N_TOK;
    int lbase = chunk * 256;

    __shared__ u16 ks_bf[32][136];
    __shared__ u16 v_bf[32][136];
    __shared__ float red[4096];
    __shared__ float redk[32], redv[32];

    int t = threadIdx.x;
    int w = t >> 6, lane = t & 63;
    int fr = lane & 15, kg = lane >> 4;

    // k-phase decomposition: pair p (0..15) x token-group g (0..15), 8 tokens each
    int p = t >> 4, g = t & 15;
    // v-phase decomposition: row d (0..31) x group g2 (0..7), 16 tokens each
    int dv = t >> 3, g2 = t & 7;

    f32x4 acc[2][2] = {};
    float ks0 = 0.f, ks1 = 0.f, vs = 0.f;

    for (int st = 0; st < 2; ++st) {
        int tok0 = lbase + st * 128;
        if (st) __syncthreads();
        // ---- issue ALL loads for this stage ----
        const float* k0p = kp + (size_t)(2 * p) * N_TOK + tok0 + g * 8;
        const float* k1p = k0p + N_TOK;
        const u32* s0p = scT + (size_t)(2 * p) * N_TOK + tok0 + g * 8;
        const u32* s1p = s0p + N_TOK;
        f32x4 k0a = ((const f32x4*)k0p)[0], k0b = ((const f32x4*)k0p)[1];
        f32x4 k1a = ((const f32x4*)k1p)[0], k1b = ((const f32x4*)k1p)[1];
        u32x4 s0a = ((const u32x4*)s0p)[0], s0b = ((const u32x4*)s0p)[1];
        u32x4 s1a = ((const u32x4*)s1p)[0], s1b = ((const u32x4*)s1p)[1];
        const float* vpp = vp + (size_t)dv * N_TOK + tok0 + g2 * 16;
        f32x4 va = ((const f32x4*)vpp)[0], vb = ((const f32x4*)vpp)[1];
        f32x4 vc = ((const f32x4*)vpp)[2], vd = ((const f32x4*)vpp)[3];

        // ---- k: elu+1, ksum, theta, pack bf16 ----
        u16 o0[8], o1[8];
#pragma unroll
        for (int j = 0; j < 8; ++j) {
            float kv0 = j < 4 ? k0a[j] : k0b[j - 4];
            float kv1 = j < 4 ? k1a[j] : k1b[j - 4];
            u32 sc0 = j < 4 ? s0a[j] : s0b[j - 4];
            u32 sc1 = j < 4 ? s1a[j] : s1b[j - 4];
            float e0 = kv0 > 0.f ? kv0 + 1.f : __expf(kv0);
            float e1 = kv1 > 0.f ? kv1 + 1.f : __expf(kv1);
            ks0 += e0; ks1 += e1;
            float se = bf_lo(sc0), ce = bf_hi(sc0);
            float so = bf_lo(sc1), co = bf_hi(sc1);
            o0[j] = f2bf(e0 * ce - e1 * se);
            o1[j] = f2bf(e1 * co + e0 * so);
        }
        u32x4 w0, w1;
#pragma unroll
        for (int q = 0; q < 4; ++q) {
            w0[q] = (u32)o0[2 * q] | ((u32)o0[2 * q + 1] << 16);
            w1[q] = (u32)o1[2 * q] | ((u32)o1[2 * q + 1] << 16);
        }
        *(u32x4*)&ks_bf[2 * p][g * 8] = w0;
        *(u32x4*)&ks_bf[2 * p + 1][g * 8] = w1;

        // ---- v: vsum, pack bf16 ----
        u16 ov[16];
#pragma unroll
        for (int j = 0; j < 4; ++j) { vs += va[j]; ov[j] = f2bf(va[j]); }
#pragma unroll
        for (int j = 0; j < 4; ++j) { vs += vb[j]; ov[4 + j] = f2bf(vb[j]); }
#pragma unroll
        for (int j = 0; j < 4; ++j) { vs += vc[j]; ov[8 + j] = f2bf(vc[j]); }
#pragma unroll
        for (int j = 0; j < 4; ++j) { vs += vd[j]; ov[12 + j] = f2bf(vd[j]); }
        u32x4 wv0, wv1;
#pragma unroll
        for (int q = 0; q < 4; ++q) {
            wv0[q] = (u32)ov[2 * q] | ((u32)ov[2 * q + 1] << 16);
            wv1[q] = (u32)ov[8 + 2 * q] | ((u32)ov[9 + 2 * q] << 16);
        }
        *(u32x4*)&v_bf[dv][g2 * 16] = wv0;
        *(u32x4*)&v_bf[dv][g2 * 16 + 8] = wv1;
        __syncthreads();

        // ---- MFMA: wave w covers staged tokens [w*32, w*32+32) ----
        int kcol = w * 32 + kg * 8;
        bf16x8 af[2], bfv[2];
#pragma unroll
        for (int i = 0; i < 2; ++i) {
            af[i]  = *(const bf16x8*)&ks_bf[i * 16 + fr][kcol];
            bfv[i] = *(const bf16x8*)&v_bf[i * 16 + fr][kcol];
        }
#pragma unroll
        for (int i = 0; i < 2; ++i)
#pragma unroll
            for (int jj = 0; jj < 2; ++jj)
                acc[i][jj] = __builtin_amdgcn_mfma_f32_16x16x32_bf16(af[i], bfv[jj], acc[i][jj], 0, 0, 0);
    }

    // ---- write per-wave kv frags ----
#pragma unroll
    for (int i = 0; i < 2; ++i)
#pragma unroll
        for (int jj = 0; jj < 2; ++jj)
#pragma unroll
            for (int r = 0; r < 4; ++r) {
                int row = i * 16 + kg * 4 + r;
                int col = jj * 16 + fr;
                red[w * 1024 + row * 32 + col] = acc[i][jj][r];
            }

    // ---- shuffle-tree sums (no LDS round trip) ----
#pragma unroll
    for (int m = 1; m < 16; m <<= 1) {
        ks0 += __shfl_xor(ks0, m);
        ks1 += __shfl_xor(ks1, m);
    }
    if ((lane & 15) == 0) { redk[2 * p] = ks0; redk[2 * p + 1] = ks1; }
#pragma unroll
    for (int m = 1; m < 8; m <<= 1) vs += __shfl_xor(vs, m);
    if ((lane & 7) == 0) redv[dv] = vs;
    __syncthreads();

    float* pkv = part_kv + ((size_t)bn * 16 + chunk) * 1024;
#pragma unroll
    for (int i = 0; i < 4; ++i) {
        int el = i * 256 + t;
        pkv[el] = red[el] + red[1024 + el] + red[2048 + el] + red[3072 + el];
    }
    if (t < 32) {
        part_ks[((size_t)bn * 16 + chunk) * 32 + t] = redk[t];
        part_vs[((size_t)bn * 16 + chunk) * 32 + t] = redv[t];
    }
}

// kv_final: sum 16 chunk partials -> kvT bf16 [e][d]; kmean/vmean
__global__ __launch_bounds__(256) void kv_final(const float* __restrict__ part_kv, const float* __restrict__ part_ks,
                                                const float* __restrict__ part_vs, u16* __restrict__ kvT_bf,
                                                float* __restrict__ kmean, float* __restrict__ vmean) {
    int bn = blockIdx.x;
    int t = threadIdx.x;
    const float* p = part_kv + (size_t)bn * 16 * 1024;
    const float s2c = SCALE_F / (float)N_TOK;
#pragma unroll
    for (int i = 0; i < 4; ++i) {
        int sl = t + i * 256;          // sl = d*32 + e
        float s = 0;
#pragma unroll
        for (int c = 0; c < 16; ++c) s += p[(size_t)c * 1024 + sl];
        float val = s * s2c;
        int d = sl >> 5, e = sl & 31;
        kvT_bf[(size_t)bn * 1024 + e * 32 + d] = f2bf(val);
    }
    if (t < 32) {
        float s = 0, sv = 0;
        for (int c = 0; c < 16; ++c) {
            s  += part_ks[((size_t)bn * 16 + c) * 32 + t];
            sv += part_vs[((size_t)bn * 16 + c) * 32 + t];
        }
        kmean[bn * 32 + t] = s * (1.f / (float)N_TOK);
        vmean[bn * 32 + t] = sv * (1.f / (float)N_TOK);
    }
}

// ---------------- attention epilogue, MFMA matvec -> resnT[b][l][c] bf16 ----------------
__global__ __launch_bounds__(256) void attn_epilogue(const float* __restrict__ qkvo, const u32* __restrict__ scT,
                                                     const u16* __restrict__ kvT_bf, const float* __restrict__ kmean,
                                                     const float* __restrict__ vmean, const u16* __restrict__ lepe,
                                                     u16* __restrict__ resnT) {
    int lt = blockIdx.x, bn = blockIdx.y;
    int b = bn >> 3, n = bn & 7;
    const float* qp = qkvo + ((size_t)b * 1024 + n * HD) * N_TOK;
    const float* op = qkvo + ((size_t)b * 1024 + 768 + n * HD) * N_TOK;
    const u16* lp = lepe + ((size_t)b * C_DIM + n * HD) * N_TOK;

    __shared__ u16 kvb[32 * 40];            // kv^T [e][d] bf16, stride 40
    __shared__ float kml[32], vml[32];
    __shared__ u16 Atile[4][64 * 40];       // per-wave q' bf16 [tok][d], stride 40
    __shared__ float Rtile[4][64 * 36];     // per-wave res f32 [tok][e], stride 36

    int t = threadIdx.x;
    int w = t >> 6, lane = t & 63;

    if (t < 128) {
        int e = t >> 2, d0 = (t & 3) * 8;
        *(uint4*)(kvb + e * 40 + d0) = *(const uint4*)(kvT_bf + (size_t)bn * 1024 + e * 32 + d0);
    }
    if (t < 32) { kml[t] = kmean[bn * 32 + t]; vml[t] = vmean[bn * 32 + t]; }
    __syncthreads();

    int token = lt * 256 + w * 64 + lane;

    float qv[32];
    float z = 0.f;
#pragma unroll
    for (int d = 0; d < 32; ++d) {
        float x_ = qp[(size_t)d * N_TOK + token];
        float e_ = x_ > 0.f ? x_ + 1.f : __expf(x_);
        qv[d] = e_;
        z += e_ * kml[d];
    }
    z *= SCALE_F;
#pragma unroll
    for (int p = 0; p < 16; ++p) {
        u32 sc0 = scT[(size_t)(2 * p) * N_TOK + token];
        u32 sc1 = scT[(size_t)(2 * p + 1) * N_TOK + token];
        float se = bf_lo(sc0), ce = bf_hi(sc0);
        float so = bf_lo(sc1), co = bf_hi(sc1);
        float a = qv[2 * p], bb = qv[2 * p + 1];
        qv[2 * p]     = a * ce - bb * se;
        qv[2 * p + 1] = bb * co + a * so;
    }
    float mult = 1.f + 1.f / (z + 1e-6f);

    u16* Aw = Atile[w];
#pragma unroll
    for (int j4 = 0; j4 < 4; ++j4) {
        uint4 u;
        u.x = (u32)f2bf(qv[8 * j4 + 0]) | ((u32)f2bf(qv[8 * j4 + 1]) << 16);
        u.y = (u32)f2bf(qv[8 * j4 + 2]) | ((u32)f2bf(qv[8 * j4 + 3]) << 16);
        u.z = (u32)f2bf(qv[8 * j4 + 4]) | ((u32)f2bf(qv[8 * j4 + 5]) << 16);
        u.w = (u32)f2bf(qv[8 * j4 + 6]) | ((u32)f2bf(qv[8 * j4 + 7]) << 16);
        *(uint4*)(Aw + lane * 40 + j4 * 8) = u;
    }
    __syncthreads();

    int fr = lane & 15, kg = lane >> 4;
    bf16x8 af[4], bfr[2];
#pragma unroll
    for (int i = 0; i < 4; ++i)
        af[i] = *(const bf16x8*)(Aw + (i * 16 + fr) * 40 + kg * 8);
#pragma unroll
    for (int jj = 0; jj < 2; ++jj)
        bfr[jj] = *(const bf16x8*)(kvb + (jj * 16 + fr) * 40 + kg * 8);

    float* Rw = Rtile[w];
    f32x4 zero = {0.f, 0.f, 0.f, 0.f};
#pragma unroll
    for (int i = 0; i < 4; ++i)
#pragma unroll
        for (int jj = 0; jj < 2; ++jj) {
            f32x4 acc = __builtin_amdgcn_mfma_f32_16x16x32_bf16(af[i], bfr[jj], zero, 0, 0, 0);
#pragma unroll
            for (int r = 0; r < 4; ++r)
                Rw[(i * 16 + kg * 4 + r) * 36 + jj * 16 + fr] = acc[r];
        }
    __syncthreads();

    float res[32];
#pragma unroll
    for (int j = 0; j < 8; ++j) {
        f32x4 vr = *(const f32x4*)(Rw + lane * 36 + j * 4);
        res[4 * j] = vr[0]; res[4 * j + 1] = vr[1]; res[4 * j + 2] = vr[2]; res[4 * j + 3] = vr[3];
    }

    u16* dst0 = resnT + ((size_t)b * N_TOK + token) * C_DIM + n * HD;
#pragma unroll
    for (int g = 0; g < 4; ++g) {
        float vv[8];
#pragma unroll
        for (int e2 = 0; e2 < 8; ++e2) {
            int ee = g * 8 + e2;
            float lx = __uint_as_float((u32)lp[(size_t)ee * N_TOK + token] << 16);
            float ov = op[(size_t)ee * N_TOK + token];
            float rx = res[ee] * mult - z * vml[ee];
            vv[e2] = (rx + lx) * ov;
        }
        uint4 u;
        u.x = (u32)f2bf(vv[0]) | ((u32)f2bf(vv[1]) << 16);
        u.y = (u32)f2bf(vv[2]) | ((u32)f2bf(vv[3]) << 16);
        u.z = (u32)f2bf(vv[4]) | ((u32)f2bf(vv[5]) << 16);
        u.w = (u32)f2bf(vv[6]) | ((u32)f2bf(vv[7]) << 16);
        ((uint4*)(dst0 + g * 8))[0] = u;
    }
}

extern "C" void kernel_launch(void* const* d_in, const int* in_sizes, int n_in,
                              void* d_out, int out_size, void* d_ws, size_t ws_size,
                              hipStream_t stream) {
    const float* x      = (const float*)d_in[0];
    const float* sinp   = (const float*)d_in[1];
    const float* cosp   = (const float*)d_in[2];
    const float* w_qkvo = (const float*)d_in[3];
    const float* b_qkvo = (const float*)d_in[4];
    const float* w_lepe = (const float*)d_in[5];
    const float* b_lepe = (const float*)d_in[6];
    const float* w_proj = (const float*)d_in[7];
    const float* b_proj = (const float*)d_in[8];

    char* ws = (char*)d_ws;
    size_t off = 0;
    auto alloc = [&](size_t bytes) { size_t o = off; off = (off + bytes + 255) & ~(size_t)255; return o; };
    u16*   wbf     = (u16*)(ws + alloc((size_t)1024 * 256 * 2));
    u16*   wpbf    = (u16*)(ws + alloc((size_t)256 * 256 * 2));
    u16*   xT      = (u16*)(ws + alloc((size_t)8 * 4096 * 256 * 2));
    float* qkvo    = (float*)(ws + alloc((size_t)8 * 1024 * 4096 * 4));
    u16*   lepe    = (u16*)(ws + alloc((size_t)8 * 256 * 4096 * 2));
    u16*   resnT   = (u16*)(ws + alloc((size_t)8 * 4096 * 256 * 2));
    float* part_kv = (float*)(ws + alloc((size_t)64 * 16 * 1024 * 4));
    float* part_ks = (float*)(ws + alloc((size_t)64 * 16 * 32 * 4));
    float* part_vs = (float*)(ws + alloc((size_t)64 * 16 * 32 * 4));
    u16*   kvT_bf  = (u16*)(ws + alloc((size_t)64 * 1024 * 2));
    float* kmean   = (float*)(ws + alloc((size_t)64 * 32 * 4));
    float* vmean   = (float*)(ws + alloc((size_t)64 * 32 * 4));
    u32*   scT     = (u32*)(ws + alloc((size_t)32 * 4096 * 4));
    if (off > ws_size) return;  // insufficient workspace -> loud validation failure

    conv_w<<<dim3(1024), dim3(256), 0, stream>>>(w_qkvo, w_proj, wbf, wpbf);
    make_sc<<<dim3(64), dim3(256), 0, stream>>>(sinp, cosp, scT);
    transpose_x<<<dim3(128, 8, 8), dim3(256), 0, stream>>>(x, xT);
    gemm_bt<<<dim3(32, 8, 8), dim3(256), 0, stream>>>(wbf, xT, b_qkvo, qkvo, 1024, 4096, 256);
    lepe_conv<<<dim3(4, 256, 8), dim3(256), 0, stream>>>(qkvo, w_lepe, b_lepe, lepe);
    kv_reduce<<<dim3(16, 64), dim3(256), 0, stream>>>(qkvo, scT, part_kv, part_ks, part_vs);
    kv_final<<<dim3(64), dim3(256), 0, stream>>>(part_kv, part_ks, part_vs, kvT_bf, kmean, vmean);
    attn_epilogue<<<dim3(16, 64), dim3(256), 0, stream>>>(qkvo, scT, kvT_bf, kmean, vmean, lepe, resnT);
    gemm_bt<<<dim3(32, 2, 8), dim3(256), 0, stream>>>(wpbf, resnT, b_proj, (float*)d_out, 256, 4096, 256);
}

// Round 6
// 117.879 us; speedup vs baseline: 1.4197x; 1.0859x over previous
//
#include <hip/hip_runtime.h>
#include <hip/hip_bf16.h>

typedef unsigned short u16;
typedef unsigned int u32;
typedef short bf16x8 __attribute__((ext_vector_type(8)));
typedef float f32x4 __attribute__((ext_vector_type(4)));
typedef u32 u32x4 __attribute__((ext_vector_type(4)));

#define N_TOK 4096
#define C_DIM 256
#define HEADS 8
#define HD 32
#define SCALE_F 0.17677669529663687f   /* 32^-0.5 */

__device__ inline u16 f2bf(float f) {
    u32 u = __float_as_uint(f);
    u += 0x7fffu + ((u >> 16) & 1u);
    return (u16)(u >> 16);
}
__device__ inline float b2f(u16 h) { return __uint_as_float((u32)h << 16); }
__device__ inline float bf_lo(u32 u) { return __uint_as_float(u << 16); }
__device__ inline float bf_hi(u32 u) { return __uint_as_float(u & 0xffff0000u); }

__device__ inline void gload16(const void* g, void* l) {
    __builtin_amdgcn_global_load_lds((const __attribute__((address_space(1))) u32*)g,
                                     (__attribute__((address_space(3))) u32*)l, 16, 0, 0);
}

__device__ inline void store_out(float* p, float v) { *p = v; }
__device__ inline void store_out(u16* p, float v) { *p = f2bf(v); }

// ---------------- weight fp32 -> bf16 ----------------
__global__ __launch_bounds__(256) void conv_w(const float* __restrict__ w1, const float* __restrict__ w2,
                                              u16* __restrict__ o1, u16* __restrict__ o2) {
    int i = blockIdx.x * 256 + threadIdx.x;
    if (i < 1024 * 256) o1[i] = f2bf(w1[i]);
    if (i < 256 * 256)  o2[i] = f2bf(w2[i]);
}

// ---------------- sin/cos [4096][32] -> packed bf16x2 scT[32][4096] (lo=sin, hi=cos) ----------------
__global__ __launch_bounds__(256) void make_sc(const float* __restrict__ s, const float* __restrict__ c,
                                               u32* __restrict__ scT) {
    int l0 = blockIdx.x * 64;
    __shared__ float ts[64][33];
    __shared__ float tc[64][33];
    int t = threadIdx.x;
    int d = t & 31, r = t >> 5;
#pragma unroll
    for (int i = 0; i < 8; ++i) {
        ts[r + i * 8][d] = s[(size_t)(l0 + r + i * 8) * HD + d];
        tc[r + i * 8][d] = c[(size_t)(l0 + r + i * 8) * HD + d];
    }
    __syncthreads();
    int li = t & 63, dr = t >> 6;
#pragma unroll
    for (int i = 0; i < 8; ++i) {
        int dd = dr * 8 + i;
        scT[(size_t)dd * N_TOK + l0 + li] = (u32)f2bf(ts[li][dd]) | ((u32)f2bf(tc[li][dd]) << 16);
    }
}

// ---------------- x[b][c][l] fp32 -> xT[b][l][c] bf16 ----------------
__global__ __launch_bounds__(256) void transpose_x(const float* __restrict__ x, u16* __restrict__ xT) {
    int b = blockIdx.z;
    int c0 = blockIdx.y * 32, l0 = blockIdx.x * 32;
    const float* xb = x + ((size_t)b * C_DIM + c0) * N_TOK + l0;
    __shared__ u16 tl[32][33];
    int t = threadIdx.x;
    int li = t & 31, ci = t >> 5;
#pragma unroll
    for (int i = 0; i < 4; ++i)
        tl[ci + i * 8][li] = f2bf(xb[(size_t)(ci + i * 8) * N_TOK + li]);
    __syncthreads();
    int c2 = t & 15, lr = t >> 4;
    u16* outp = xT + ((size_t)b * N_TOK + l0) * C_DIM + c0;
#pragma unroll
    for (int i = 0; i < 2; ++i) {
        int l = lr + i * 16;
        u32 pv = (u32)tl[2 * c2][l] | ((u32)tl[2 * c2 + 1][l] << 16);
        *(u32*)(outp + (size_t)l * C_DIM + 2 * c2) = pv;
    }
}

// ---------------- bf16 MFMA GEMM, BK=64, XOR slot swizzle; templated output dtype ----------------
template <typename TO>
__global__ __launch_bounds__(256) void gemm_bt(const u16* __restrict__ A, const u16* __restrict__ Bm,
                                               const float* __restrict__ bias, TO* __restrict__ C,
                                               int M, int L, int K) {
    int bt = blockIdx.z;
    int m0 = blockIdx.y * 128;
    int l0 = blockIdx.x * 128;
    const u16* Bb = Bm + (size_t)bt * L * K;
    TO* Cb = C + (size_t)bt * M * L;

    __shared__ u16 As[128 * 64];
    __shared__ u16 Bs[128 * 64];

    int t = threadIdx.x;
    int w = t >> 6, lane = t & 63;
    int wr = (w >> 1) * 64, wc = (w & 1) * 64;
    int fr = lane & 15, kg = lane >> 4;

    f32x4 acc[4][4] = {};

    for (int k0 = 0; k0 < K; k0 += 64) {
#pragma unroll
        for (int j = 0; j < 4; ++j) {
            int c = j * 256 + w * 64 + lane;
            int row = c >> 3, slot = c & 7;
            int gslot = slot ^ (row & 7);
            u16* abase = (u16*)As + (size_t)(j * 256 + w * 64) * 8;
            u16* bbase = (u16*)Bs + (size_t)(j * 256 + w * 64) * 8;
            gload16(A + (size_t)(m0 + row) * K + k0 + gslot * 8, abase);
            gload16(Bb + (size_t)(l0 + row) * K + k0 + gslot * 8, bbase);
        }
        __syncthreads();
#pragma unroll
        for (int kk = 0; kk < 2; ++kk) {
            bf16x8 af[4], bfr[4];
#pragma unroll
            for (int i = 0; i < 4; ++i) {
                int ra = wr + i * 16 + fr;
                int rb = wc + i * 16 + fr;
                af[i]  = *(const bf16x8*)(As + (size_t)ra * 64 + (size_t)((kk * 4 + kg) ^ (ra & 7)) * 8);
                bfr[i] = *(const bf16x8*)(Bs + (size_t)rb * 64 + (size_t)((kk * 4 + kg) ^ (rb & 7)) * 8);
            }
#pragma unroll
            for (int i = 0; i < 4; ++i)
#pragma unroll
                for (int jj = 0; jj < 4; ++jj)
                    acc[i][jj] = __builtin_amdgcn_mfma_f32_16x16x32_bf16(af[i], bfr[jj], acc[i][jj], 0, 0, 0);
        }
        __syncthreads();
    }

    int rg = (lane >> 4) * 4;
#pragma unroll
    for (int i = 0; i < 4; ++i)
#pragma unroll
        for (int jj = 0; jj < 4; ++jj) {
            int col = l0 + wc + jj * 16 + fr;
#pragma unroll
            for (int r = 0; r < 4; ++r) {
                int row = m0 + wr + i * 16 + rg + r;
                store_out(Cb + (size_t)row * L + col, acc[i][jj][r] + bias[row]);
            }
        }
}

// ---------------- lepe: depthwise 5x5, pad 2, on bf16 v channels -> bf16 ----------------
__global__ __launch_bounds__(256) void lepe_conv(const u16* __restrict__ qkvo, const float* __restrict__ wl,
                                                 const float* __restrict__ bl, u16* __restrict__ lepe) {
    int ht = blockIdx.x, c = blockIdx.y, b = blockIdx.z;
    const u16* src = qkvo + ((size_t)b * 1024 + 512 + c) * N_TOK;
    u16* dst = lepe + ((size_t)b * C_DIM + c) * N_TOK;
    __shared__ float tile[20][72];
    __shared__ float wcoef[25];
    int t = threadIdx.x;
    if (t < 25) wcoef[t] = wl[c * 25 + t];
    int h0 = ht * 16;
    for (int i = t; i < 20 * 72; i += 256) {
        int r = i / 72, cc = i % 72;
        int gh = h0 + r - 2, gw = cc - 4;
        float v = 0.f;
        if (gh >= 0 && gh < 64 && gw >= 0 && gw < 64) v = b2f(src[gh * 64 + gw]);
        tile[r][cc] = v;
    }
    __syncthreads();
    int wq = t & 15, hh = t >> 4;
    int w0 = wq * 4;
    float bb = bl[c];
    float acc[4] = {bb, bb, bb, bb};
#pragma unroll
    for (int i = 0; i < 5; ++i) {
        const float* rowp = &tile[hh + i][0];
        float4 a0 = *(const float4*)(rowp + w0);
        float4 a1 = *(const float4*)(rowp + w0 + 4);
        float4 a2 = *(const float4*)(rowp + w0 + 8);
        float f[12] = {a0.x, a0.y, a0.z, a0.w, a1.x, a1.y, a1.z, a1.w, a2.x, a2.y, a2.z, a2.w};
#pragma unroll
        for (int jj = 0; jj < 5; ++jj) {
            float wv_ = wcoef[i * 5 + jj];
#pragma unroll
            for (int ow = 0; ow < 4; ++ow)
                acc[ow] += f[ow + jj + 2] * wv_;
        }
    }
    int h = h0 + hh;
    uint2 pv;
    pv.x = (u32)f2bf(acc[0]) | ((u32)f2bf(acc[1]) << 16);
    pv.y = (u32)f2bf(acc[2]) | ((u32)f2bf(acc[3]) << 16);
    *(uint2*)(dst + h * 64 + w0) = pv;
}

// ---------------- kv reduction via MFMA, batched vector staging, bf16 input ----------------
__global__ __launch_bounds__(256) void kv_reduce(const u16* __restrict__ qkvo, const u32* __restrict__ scT,
                                                 float* __restrict__ part_kv, float* __restrict__ part_ks,
                                                 float* __restrict__ part_vs) {
    int chunk = blockIdx.x, bn = blockIdx.y;
    int b = bn >> 3, n = bn & 7;
    const u16* kp = qkvo + ((size_t)b * 1024 + 256 + n * HD) * N_TOK;
    const u16* vp = qkvo + ((size_t)b * 1024 + 512 + n * HD) * N_TOK;
    int lbase = chunk * 256;

    __shared__ u16 ks_bf[32][136];
    __shared__ u16 v_bf[32][136];
    __shared__ float red[4096];
    __shared__ float redk[32], redv[32];

    int t = threadIdx.x;
    int w = t >> 6, lane = t & 63;
    int fr = lane & 15, kg = lane >> 4;

    int p = t >> 4, g = t & 15;       // k-phase: pair p x token-group g (8 tokens)
    int dv = t >> 3, g2 = t & 7;      // v-phase: row dv x group g2 (16 tokens)

    f32x4 acc[2][2] = {};
    float ks0 = 0.f, ks1 = 0.f, vs = 0.f;

    for (int st = 0; st < 2; ++st) {
        int tok0 = lbase + st * 128;
        if (st) __syncthreads();
        // ---- issue ALL loads for this stage ----
        const u16* k0p = kp + (size_t)(2 * p) * N_TOK + tok0 + g * 8;
        const u16* k1p = k0p + N_TOK;
        const u32* s0p = scT + (size_t)(2 * p) * N_TOK + tok0 + g * 8;
        const u32* s1p = s0p + N_TOK;
        bf16x8 k0 = *(const bf16x8*)k0p;
        bf16x8 k1 = *(const bf16x8*)k1p;
        u32x4 s0a = ((const u32x4*)s0p)[0], s0b = ((const u32x4*)s0p)[1];
        u32x4 s1a = ((const u32x4*)s1p)[0], s1b = ((const u32x4*)s1p)[1];
        const u16* vpp = vp + (size_t)dv * N_TOK + tok0 + g2 * 16;
        bf16x8 va = ((const bf16x8*)vpp)[0];
        bf16x8 vb = ((const bf16x8*)vpp)[1];

        // ---- k: elu+1, ksum, theta, pack bf16 ----
        u16 o0[8], o1[8];
#pragma unroll
        for (int j = 0; j < 8; ++j) {
            float kv0 = b2f((u16)k0[j]);
            float kv1 = b2f((u16)k1[j]);
            u32 sc0 = j < 4 ? s0a[j] : s0b[j - 4];
            u32 sc1 = j < 4 ? s1a[j] : s1b[j - 4];
            float e0 = kv0 > 0.f ? kv0 + 1.f : __expf(kv0);
            float e1 = kv1 > 0.f ? kv1 + 1.f : __expf(kv1);
            ks0 += e0; ks1 += e1;
            float se = bf_lo(sc0), ce = bf_hi(sc0);
            float so = bf_lo(sc1), co = bf_hi(sc1);
            o0[j] = f2bf(e0 * ce - e1 * se);
            o1[j] = f2bf(e1 * co + e0 * so);
        }
        u32x4 w0, w1;
#pragma unroll
        for (int q = 0; q < 4; ++q) {
            w0[q] = (u32)o0[2 * q] | ((u32)o0[2 * q + 1] << 16);
            w1[q] = (u32)o1[2 * q] | ((u32)o1[2 * q + 1] << 16);
        }
        *(u32x4*)&ks_bf[2 * p][g * 8] = w0;
        *(u32x4*)&ks_bf[2 * p + 1][g * 8] = w1;

        // ---- v: vsum fp32; stage raw bf16 bits ----
#pragma unroll
        for (int j = 0; j < 8; ++j) { vs += b2f((u16)va[j]); }
#pragma unroll
        for (int j = 0; j < 8; ++j) { vs += b2f((u16)vb[j]); }
        *(bf16x8*)&v_bf[dv][g2 * 16] = va;
        *(bf16x8*)&v_bf[dv][g2 * 16 + 8] = vb;
        __syncthreads();

        // ---- MFMA: wave w covers staged tokens [w*32, w*32+32) ----
        int kcol = w * 32 + kg * 8;
        bf16x8 af[2], bfv[2];
#pragma unroll
        for (int i = 0; i < 2; ++i) {
            af[i]  = *(const bf16x8*)&ks_bf[i * 16 + fr][kcol];
            bfv[i] = *(const bf16x8*)&v_bf[i * 16 + fr][kcol];
        }
#pragma unroll
        for (int i = 0; i < 2; ++i)
#pragma unroll
            for (int jj = 0; jj < 2; ++jj)
                acc[i][jj] = __builtin_amdgcn_mfma_f32_16x16x32_bf16(af[i], bfv[jj], acc[i][jj], 0, 0, 0);
    }

    // ---- write per-wave kv frags ----
#pragma unroll
    for (int i = 0; i < 2; ++i)
#pragma unroll
        for (int jj = 0; jj < 2; ++jj)
#pragma unroll
            for (int r = 0; r < 4; ++r) {
                int row = i * 16 + kg * 4 + r;
                int col = jj * 16 + fr;
                red[w * 1024 + row * 32 + col] = acc[i][jj][r];
            }

    // ---- shuffle-tree sums ----
#pragma unroll
    for (int m = 1; m < 16; m <<= 1) {
        ks0 += __shfl_xor(ks0, m);
        ks1 += __shfl_xor(ks1, m);
    }
    if ((lane & 15) == 0) { redk[2 * p] = ks0; redk[2 * p + 1] = ks1; }
#pragma unroll
    for (int m = 1; m < 8; m <<= 1) vs += __shfl_xor(vs, m);
    if ((lane & 7) == 0) redv[dv] = vs;
    __syncthreads();

    float* pkv = part_kv + ((size_t)bn * 16 + chunk) * 1024;
#pragma unroll
    for (int i = 0; i < 4; ++i) {
        int el = i * 256 + t;
        pkv[el] = red[el] + red[1024 + el] + red[2048 + el] + red[3072 + el];
    }
    if (t < 32) {
        part_ks[((size_t)bn * 16 + chunk) * 32 + t] = redk[t];
        part_vs[((size_t)bn * 16 + chunk) * 32 + t] = redv[t];
    }
}

// kv_final: sum 16 chunk partials -> kvT bf16 [e][d]; kmean/vmean
__global__ __launch_bounds__(256) void kv_final(const float* __restrict__ part_kv, const float* __restrict__ part_ks,
                                                const float* __restrict__ part_vs, u16* __restrict__ kvT_bf,
                                                float* __restrict__ kmean, float* __restrict__ vmean) {
    int bn = blockIdx.x;
    int t = threadIdx.x;
    const float* p = part_kv + (size_t)bn * 16 * 1024;
    const float s2c = SCALE_F / (float)N_TOK;
#pragma unroll
    for (int i = 0; i < 4; ++i) {
        int sl = t + i * 256;          // sl = d*32 + e
        float s = 0;
#pragma unroll
        for (int c = 0; c < 16; ++c) s += p[(size_t)c * 1024 + sl];
        float val = s * s2c;
        int d = sl >> 5, e = sl & 31;
        kvT_bf[(size_t)bn * 1024 + e * 32 + d] = f2bf(val);
    }
    if (t < 32) {
        float s = 0, sv = 0;
        for (int c = 0; c < 16; ++c) {
            s  += part_ks[((size_t)bn * 16 + c) * 32 + t];
            sv += part_vs[((size_t)bn * 16 + c) * 32 + t];
        }
        kmean[bn * 32 + t] = s * (1.f / (float)N_TOK);
        vmean[bn * 32 + t] = sv * (1.f / (float)N_TOK);
    }
}

// ---------------- attention epilogue, MFMA matvec -> resnT[b][l][c] bf16 ----------------
__global__ __launch_bounds__(256) void attn_epilogue(const u16* __restrict__ qkvo, const u32* __restrict__ scT,
                                                     const u16* __restrict__ kvT_bf, const float* __restrict__ kmean,
                                                     const float* __restrict__ vmean, const u16* __restrict__ lepe,
                                                     u16* __restrict__ resnT) {
    int lt = blockIdx.x, bn = blockIdx.y;
    int b = bn >> 3, n = bn & 7;
    const u16* qp = qkvo + ((size_t)b * 1024 + n * HD) * N_TOK;
    const u16* op = qkvo + ((size_t)b * 1024 + 768 + n * HD) * N_TOK;
    const u16* lp = lepe + ((size_t)b * C_DIM + n * HD) * N_TOK;

    __shared__ u16 kvb[32 * 40];            // kv^T [e][d] bf16, stride 40
    __shared__ float kml[32], vml[32];
    __shared__ u16 Atile[4][64 * 40];       // per-wave q' bf16 [tok][d], stride 40
    __shared__ float Rtile[4][64 * 36];     // per-wave res f32 [tok][e], stride 36

    int t = threadIdx.x;
    int w = t >> 6, lane = t & 63;

    if (t < 128) {
        int e = t >> 2, d0 = (t & 3) * 8;
        *(uint4*)(kvb + e * 40 + d0) = *(const uint4*)(kvT_bf + (size_t)bn * 1024 + e * 32 + d0);
    }
    if (t < 32) { kml[t] = kmean[bn * 32 + t]; vml[t] = vmean[bn * 32 + t]; }
    __syncthreads();

    int token = lt * 256 + w * 64 + lane;

    float qv[32];
    float z = 0.f;
#pragma unroll
    for (int d = 0; d < 32; ++d) {
        float x_ = b2f(qp[(size_t)d * N_TOK + token]);
        float e_ = x_ > 0.f ? x_ + 1.f : __expf(x_);
        qv[d] = e_;
        z += e_ * kml[d];
    }
    z *= SCALE_F;
#pragma unroll
    for (int p = 0; p < 16; ++p) {
        u32 sc0 = scT[(size_t)(2 * p) * N_TOK + token];
        u32 sc1 = scT[(size_t)(2 * p + 1) * N_TOK + token];
        float se = bf_lo(sc0), ce = bf_hi(sc0);
        float so = bf_lo(sc1), co = bf_hi(sc1);
        float a = qv[2 * p], bb = qv[2 * p + 1];
        qv[2 * p]     = a * ce - bb * se;
        qv[2 * p + 1] = bb * co + a * so;
    }
    float mult = 1.f + 1.f / (z + 1e-6f);

    u16* Aw = Atile[w];
#pragma unroll
    for (int j4 = 0; j4 < 4; ++j4) {
        uint4 u;
        u.x = (u32)f2bf(qv[8 * j4 + 0]) | ((u32)f2bf(qv[8 * j4 + 1]) << 16);
        u.y = (u32)f2bf(qv[8 * j4 + 2]) | ((u32)f2bf(qv[8 * j4 + 3]) << 16);
        u.z = (u32)f2bf(qv[8 * j4 + 4]) | ((u32)f2bf(qv[8 * j4 + 5]) << 16);
        u.w = (u32)f2bf(qv[8 * j4 + 6]) | ((u32)f2bf(qv[8 * j4 + 7]) << 16);
        *(uint4*)(Aw + lane * 40 + j4 * 8) = u;
    }
    __syncthreads();

    int fr = lane & 15, kg = lane >> 4;
    bf16x8 af[4], bfr[2];
#pragma unroll
    for (int i = 0; i < 4; ++i)
        af[i] = *(const bf16x8*)(Aw + (i * 16 + fr) * 40 + kg * 8);
#pragma unroll
    for (int jj = 0; jj < 2; ++jj)
        bfr[jj] = *(const bf16x8*)(kvb + (jj * 16 + fr) * 40 + kg * 8);

    float* Rw = Rtile[w];
    f32x4 zero = {0.f, 0.f, 0.f, 0.f};
#pragma unroll
    for (int i = 0; i < 4; ++i)
#pragma unroll
        for (int jj = 0; jj < 2; ++jj) {
            f32x4 acc = __builtin_amdgcn_mfma_f32_16x16x32_bf16(af[i], bfr[jj], zero, 0, 0, 0);
#pragma unroll
            for (int r = 0; r < 4; ++r)
                Rw[(i * 16 + kg * 4 + r) * 36 + jj * 16 + fr] = acc[r];
        }
    __syncthreads();

    float res[32];
#pragma unroll
    for (int j = 0; j < 8; ++j) {
        f32x4 vr = *(const f32x4*)(Rw + lane * 36 + j * 4);
        res[4 * j] = vr[0]; res[4 * j + 1] = vr[1]; res[4 * j + 2] = vr[2]; res[4 * j + 3] = vr[3];
    }

    u16* dst0 = resnT + ((size_t)b * N_TOK + token) * C_DIM + n * HD;
#pragma unroll
    for (int g = 0; g < 4; ++g) {
        float vv[8];
#pragma unroll
        for (int e2 = 0; e2 < 8; ++e2) {
            int ee = g * 8 + e2;
            float lx = b2f(lp[(size_t)ee * N_TOK + token]);
            float ov = b2f(op[(size_t)ee * N_TOK + token]);
            float rx = res[ee] * mult - z * vml[ee];
            vv[e2] = (rx + lx) * ov;
        }
        uint4 u;
        u.x = (u32)f2bf(vv[0]) | ((u32)f2bf(vv[1]) << 16);
        u.y = (u32)f2bf(vv[2]) | ((u32)f2bf(vv[3]) << 16);
        u.z = (u32)f2bf(vv[4]) | ((u32)f2bf(vv[5]) << 16);
        u.w = (u32)f2bf(vv[6]) | ((u32)f2bf(vv[7]) << 16);
        ((uint4*)(dst0 + g * 8))[0] = u;
    }
}

extern "C" void kernel_launch(void* const* d_in, const int* in_sizes, int n_in,
                              void* d_out, int out_size, void* d_ws, size_t ws_size,
                              hipStream_t stream) {
    const float* x      = (const float*)d_in[0];
    const float* sinp   = (const float*)d_in[1];
    const float* cosp   = (const float*)d_in[2];
    const float* w_qkvo = (const float*)d_in[3];
    const float* b_qkvo = (const float*)d_in[4];
    const float* w_lepe = (const float*)d_in[5];
    const float* b_lepe = (const float*)d_in[6];
    const float* w_proj = (const float*)d_in[7];
    const float* b_proj = (const float*)d_in[8];

    char* ws = (char*)d_ws;
    size_t off = 0;
    auto alloc = [&](size_t bytes) { size_t o = off; off = (off + bytes + 255) & ~(size_t)255; return o; };
    u16*   wbf     = (u16*)(ws + alloc((size_t)1024 * 256 * 2));
    u16*   wpbf    = (u16*)(ws + alloc((size_t)256 * 256 * 2));
    u16*   xT      = (u16*)(ws + alloc((size_t)8 * 4096 * 256 * 2));
    u16*   qkvo    = (u16*)(ws + alloc((size_t)8 * 1024 * 4096 * 2));
    u16*   lepe    = (u16*)(ws + alloc((size_t)8 * 256 * 4096 * 2));
    u16*   resnT   = (u16*)(ws + alloc((size_t)8 * 4096 * 256 * 2));
    float* part_kv = (float*)(ws + alloc((size_t)64 * 16 * 1024 * 4));
    float* part_ks = (float*)(ws + alloc((size_t)64 * 16 * 32 * 4));
    float* part_vs = (float*)(ws + alloc((size_t)64 * 16 * 32 * 4));
    u16*   kvT_bf  = (u16*)(ws + alloc((size_t)64 * 1024 * 2));
    float* kmean   = (float*)(ws + alloc((size_t)64 * 32 * 4));
    float* vmean   = (float*)(ws + alloc((size_t)64 * 32 * 4));
    u32*   scT     = (u32*)(ws + alloc((size_t)32 * 4096 * 4));
    if (off > ws_size) return;  // insufficient workspace -> loud validation failure

    conv_w<<<dim3(1024), dim3(256), 0, stream>>>(w_qkvo, w_proj, wbf, wpbf);
    make_sc<<<dim3(64), dim3(256), 0, stream>>>(sinp, cosp, scT);
    transpose_x<<<dim3(128, 8, 8), dim3(256), 0, stream>>>(x, xT);
    gemm_bt<u16><<<dim3(32, 8, 8), dim3(256), 0, stream>>>(wbf, xT, b_qkvo, qkvo, 1024, 4096, 256);
    lepe_conv<<<dim3(4, 256, 8), dim3(256), 0, stream>>>(qkvo, w_lepe, b_lepe, lepe);
    kv_reduce<<<dim3(16, 64), dim3(256), 0, stream>>>(qkvo, scT, part_kv, part_ks, part_vs);
    kv_final<<<dim3(64), dim3(256), 0, stream>>>(part_kv, part_ks, part_vs, kvT_bf, kmean, vmean);
    attn_epilogue<<<dim3(16, 64), dim3(256), 0, stream>>>(qkvo, scT, kvT_bf, kmean, vmean, lepe, resnT);
    gemm_bt<float><<<dim3(32, 2, 8), dim3(256), 0, stream>>>(wpbf, resnT, b_proj, (float*)d_out, 256, 4096, 256);
}

// Round 7
// 111.997 us; speedup vs baseline: 1.4943x; 1.0525x over previous
//
#include <hip/hip_runtime.h>
#include <hip/hip_bf16.h>

typedef unsigned short u16;
typedef unsigned int u32;
typedef short bf16x8 __attribute__((ext_vector_type(8)));
typedef float f32x4 __attribute__((ext_vector_type(4)));
typedef u32 u32x4 __attribute__((ext_vector_type(4)));

#define N_TOK 4096
#define C_DIM 256
#define HEADS 8
#define HD 32
#define SCALE_F 0.17677669529663687f   /* 32^-0.5 */

__device__ inline u16 f2bf(float f) {
    u32 u = __float_as_uint(f);
    u += 0x7fffu + ((u >> 16) & 1u);
    return (u16)(u >> 16);
}
__device__ inline float b2f(u16 h) { return __uint_as_float((u32)h << 16); }
__device__ inline float bf_lo(u32 u) { return __uint_as_float(u << 16); }
__device__ inline float bf_hi(u32 u) { return __uint_as_float(u & 0xffff0000u); }

__device__ inline void gload16(const void* g, void* l) {
    __builtin_amdgcn_global_load_lds((const __attribute__((address_space(1))) u32*)g,
                                     (__attribute__((address_space(3))) u32*)l, 16, 0, 0);
}

__device__ inline void store_out(float* p, float v) { *p = v; }
__device__ inline void store_out(u16* p, float v) { *p = f2bf(v); }

// ---------------- weight fp32 -> bf16 ----------------
__global__ __launch_bounds__(256) void conv_w(const float* __restrict__ w1, const float* __restrict__ w2,
                                              u16* __restrict__ o1, u16* __restrict__ o2) {
    int i = blockIdx.x * 256 + threadIdx.x;
    if (i < 1024 * 256) o1[i] = f2bf(w1[i]);
    if (i < 256 * 256)  o2[i] = f2bf(w2[i]);
}

// ---------------- sin/cos [4096][32] -> packed bf16x2 scT[32][4096] (lo=sin, hi=cos) ----------------
__global__ __launch_bounds__(256) void make_sc(const float* __restrict__ s, const float* __restrict__ c,
                                               u32* __restrict__ scT) {
    int l0 = blockIdx.x * 64;
    __shared__ float ts[64][33];
    __shared__ float tc[64][33];
    int t = threadIdx.x;
    int d = t & 31, r = t >> 5;
#pragma unroll
    for (int i = 0; i < 8; ++i) {
        ts[r + i * 8][d] = s[(size_t)(l0 + r + i * 8) * HD + d];
        tc[r + i * 8][d] = c[(size_t)(l0 + r + i * 8) * HD + d];
    }
    __syncthreads();
    int li = t & 63, dr = t >> 6;
#pragma unroll
    for (int i = 0; i < 8; ++i) {
        int dd = dr * 8 + i;
        scT[(size_t)dd * N_TOK + l0 + li] = (u32)f2bf(ts[li][dd]) | ((u32)f2bf(tc[li][dd]) << 16);
    }
}

// ---------------- x[b][c][l] fp32 -> xT[b][l][c] bf16 ----------------
__global__ __launch_bounds__(256) void transpose_x(const float* __restrict__ x, u16* __restrict__ xT) {
    int b = blockIdx.z;
    int c0 = blockIdx.y * 32, l0 = blockIdx.x * 32;
    const float* xb = x + ((size_t)b * C_DIM + c0) * N_TOK + l0;
    __shared__ u16 tl[32][33];
    int t = threadIdx.x;
    int li = t & 31, ci = t >> 5;
#pragma unroll
    for (int i = 0; i < 4; ++i)
        tl[ci + i * 8][li] = f2bf(xb[(size_t)(ci + i * 8) * N_TOK + li]);
    __syncthreads();
    int c2 = t & 15, lr = t >> 4;
    u16* outp = xT + ((size_t)b * N_TOK + l0) * C_DIM + c0;
#pragma unroll
    for (int i = 0; i < 2; ++i) {
        int l = lr + i * 16;
        u32 pv = (u32)tl[2 * c2][l] | ((u32)tl[2 * c2 + 1][l] << 16);
        *(u32*)(outp + (size_t)l * C_DIM + 2 * c2) = pv;
    }
}

// ---------------- bf16 MFMA GEMM, BK=64, XOR slot swizzle; templated output dtype ----------------
// For TO=u16: C-store staged through LDS for coalesced dwordx4 global writes.
template <typename TO>
__global__ __launch_bounds__(256) void gemm_bt(const u16* __restrict__ A, const u16* __restrict__ Bm,
                                               const float* __restrict__ bias, TO* __restrict__ C,
                                               int M, int L, int K) {
    int bt = blockIdx.z;
    int m0 = blockIdx.y * 128;
    int l0 = blockIdx.x * 128;
    const u16* Bb = Bm + (size_t)bt * L * K;
    TO* Cb = C + (size_t)bt * M * L;

    __shared__ u16 smem[17408];           // As(8192) + Bs(8192); reused as Cs[128][136]
    u16* As = smem;
    u16* Bs = smem + 8192;
    u16* Cs = smem;

    int t = threadIdx.x;
    int w = t >> 6, lane = t & 63;
    int wr = (w >> 1) * 64, wc = (w & 1) * 64;
    int fr = lane & 15, kg = lane >> 4;

    f32x4 acc[4][4] = {};

    for (int k0 = 0; k0 < K; k0 += 64) {
#pragma unroll
        for (int j = 0; j < 4; ++j) {
            int c = j * 256 + w * 64 + lane;
            int row = c >> 3, slot = c & 7;
            int gslot = slot ^ (row & 7);
            u16* abase = As + (size_t)(j * 256 + w * 64) * 8;
            u16* bbase = Bs + (size_t)(j * 256 + w * 64) * 8;
            gload16(A + (size_t)(m0 + row) * K + k0 + gslot * 8, abase);
            gload16(Bb + (size_t)(l0 + row) * K + k0 + gslot * 8, bbase);
        }
        __syncthreads();
#pragma unroll
        for (int kk = 0; kk < 2; ++kk) {
            bf16x8 af[4], bfr[4];
#pragma unroll
            for (int i = 0; i < 4; ++i) {
                int ra = wr + i * 16 + fr;
                int rb = wc + i * 16 + fr;
                af[i]  = *(const bf16x8*)(As + (size_t)ra * 64 + (size_t)((kk * 4 + kg) ^ (ra & 7)) * 8);
                bfr[i] = *(const bf16x8*)(Bs + (size_t)rb * 64 + (size_t)((kk * 4 + kg) ^ (rb & 7)) * 8);
            }
#pragma unroll
            for (int i = 0; i < 4; ++i)
#pragma unroll
                for (int jj = 0; jj < 4; ++jj)
                    acc[i][jj] = __builtin_amdgcn_mfma_f32_16x16x32_bf16(af[i], bfr[jj], acc[i][jj], 0, 0, 0);
        }
        __syncthreads();
    }

    int rg = (lane >> 4) * 4;
    if constexpr (sizeof(TO) == 2) {
        // stage bf16 C tile in LDS, then coalesced 16B stores
#pragma unroll
        for (int i = 0; i < 4; ++i)
#pragma unroll
            for (int jj = 0; jj < 4; ++jj) {
                int col = wc + jj * 16 + fr;
#pragma unroll
                for (int r = 0; r < 4; ++r) {
                    int row = wr + i * 16 + rg + r;
                    Cs[row * 136 + col] = f2bf(acc[i][jj][r] + bias[m0 + row]);
                }
            }
        __syncthreads();
        u16* CbT = (u16*)Cb;
#pragma unroll
        for (int j = 0; j < 8; ++j) {
            int id = j * 256 + t;
            int row = id >> 4, c8 = (id & 15) * 8;
            *(uint4*)(CbT + (size_t)(m0 + row) * L + l0 + c8) = *(const uint4*)(Cs + row * 136 + c8);
        }
    } else {
#pragma unroll
        for (int i = 0; i < 4; ++i)
#pragma unroll
            for (int jj = 0; jj < 4; ++jj) {
                int col = l0 + wc + jj * 16 + fr;
#pragma unroll
                for (int r = 0; r < 4; ++r) {
                    int row = m0 + wr + i * 16 + rg + r;
                    store_out(Cb + (size_t)row * L + col, acc[i][jj][r] + bias[row]);
                }
            }
    }
}

// ---------------- lepe: depthwise 5x5, pad 2 — one block per (channel, batch), L1-direct ----------------
__global__ __launch_bounds__(256) void lepe_conv(const u16* __restrict__ qkvo, const float* __restrict__ wl,
                                                 const float* __restrict__ bl, u16* __restrict__ lepe) {
    int c = blockIdx.x, b = blockIdx.y;
    const u16* src = qkvo + ((size_t)b * 1024 + 512 + c) * N_TOK;
    u16* dst = lepe + ((size_t)b * C_DIM + c) * N_TOK;
    __shared__ float wc5[25];
    int t = threadIdx.x;
    if (t < 25) wc5[t] = wl[c * 25 + t];
    __syncthreads();

    int h = t >> 2, w0 = (t & 3) * 16;     // 16 outputs: row h, cols w0..w0+15
    float bb = bl[c];
    float o16[16];
#pragma unroll
    for (int i = 0; i < 16; ++i) o16[i] = bb;

#pragma unroll
    for (int dh = 0; dh < 5; ++dh) {
        int gr = h + dh - 2;
        bool rowok = (gr >= 0) && (gr < 64);
        const u16* rp = src + (size_t)(rowok ? gr : 0) * 64 + w0 - 8;   // aligned 16B window [w0-8, w0+24)
        bf16x8 L0 = ((const bf16x8*)rp)[0];
        bf16x8 L1 = ((const bf16x8*)rp)[1];
        bf16x8 L2 = ((const bf16x8*)rp)[2];
        bf16x8 L3 = ((const bf16x8*)rp)[3];
        float rbuf[32];
#pragma unroll
        for (int j = 0; j < 32; ++j) {
            int col = w0 - 8 + j;
            u16 raw = (u16)(j < 8 ? L0[j] : j < 16 ? L1[j - 8] : j < 24 ? L2[j - 16] : L3[j - 24]);
            bool ok = rowok && (col >= 0) && (col < 64);
            rbuf[j] = ok ? b2f(raw) : 0.f;
        }
#pragma unroll
        for (int dw = 0; dw < 5; ++dw) {
            float wv_ = wc5[dh * 5 + dw];
#pragma unroll
            for (int ow = 0; ow < 16; ++ow)
                o16[ow] += rbuf[6 + dw + ow] * wv_;
        }
    }

    uint4 u0, u1;
    u0.x = (u32)f2bf(o16[0]) | ((u32)f2bf(o16[1]) << 16);
    u0.y = (u32)f2bf(o16[2]) | ((u32)f2bf(o16[3]) << 16);
    u0.z = (u32)f2bf(o16[4]) | ((u32)f2bf(o16[5]) << 16);
    u0.w = (u32)f2bf(o16[6]) | ((u32)f2bf(o16[7]) << 16);
    u1.x = (u32)f2bf(o16[8]) | ((u32)f2bf(o16[9]) << 16);
    u1.y = (u32)f2bf(o16[10]) | ((u32)f2bf(o16[11]) << 16);
    u1.z = (u32)f2bf(o16[12]) | ((u32)f2bf(o16[13]) << 16);
    u1.w = (u32)f2bf(o16[14]) | ((u32)f2bf(o16[15]) << 16);
    *(uint4*)(dst + h * 64 + w0) = u0;
    *(uint4*)(dst + h * 64 + w0 + 8) = u1;
}

// ---------------- kv reduction via MFMA, batched vector staging, bf16 input ----------------
__global__ __launch_bounds__(256) void kv_reduce(const u16* __restrict__ qkvo, const u32* __restrict__ scT,
                                                 float* __restrict__ part_kv, float* __restrict__ part_ks,
                                                 float* __restrict__ part_vs) {
    int chunk = blockIdx.x, bn = blockIdx.y;
    int b = bn >> 3, n = bn & 7;
    const u16* kp = qkvo + ((size_t)b * 1024 + 256 + n * HD) * N_TOK;
    const u16* vp = qkvo + ((size_t)b * 1024 + 512 + n * HD) * N_TOK;
    int lbase = chunk * 256;

    __shared__ u16 ks_bf[32][136];
    __shared__ u16 v_bf[32][136];
    __shared__ float red[4096];
    __shared__ float redk[32], redv[32];

    int t = threadIdx.x;
    int w = t >> 6, lane = t & 63;
    int fr = lane & 15, kg = lane >> 4;

    int p = t >> 4, g = t & 15;       // k-phase: pair p x token-group g (8 tokens)
    int dv = t >> 3, g2 = t & 7;      // v-phase: row dv x group g2 (16 tokens)

    f32x4 acc[2][2] = {};
    float ks0 = 0.f, ks1 = 0.f, vs = 0.f;

    for (int st = 0; st < 2; ++st) {
        int tok0 = lbase + st * 128;
        if (st) __syncthreads();
        const u16* k0p = kp + (size_t)(2 * p) * N_TOK + tok0 + g * 8;
        const u16* k1p = k0p + N_TOK;
        const u32* s0p = scT + (size_t)(2 * p) * N_TOK + tok0 + g * 8;
        const u32* s1p = s0p + N_TOK;
        bf16x8 k0 = *(const bf16x8*)k0p;
        bf16x8 k1 = *(const bf16x8*)k1p;
        u32x4 s0a = ((const u32x4*)s0p)[0], s0b = ((const u32x4*)s0p)[1];
        u32x4 s1a = ((const u32x4*)s1p)[0], s1b = ((const u32x4*)s1p)[1];
        const u16* vpp = vp + (size_t)dv * N_TOK + tok0 + g2 * 16;
        bf16x8 va = ((const bf16x8*)vpp)[0];
        bf16x8 vb = ((const bf16x8*)vpp)[1];

        u16 o0[8], o1[8];
#pragma unroll
        for (int j = 0; j < 8; ++j) {
            float kv0 = b2f((u16)k0[j]);
            float kv1 = b2f((u16)k1[j]);
            u32 sc0 = j < 4 ? s0a[j] : s0b[j - 4];
            u32 sc1 = j < 4 ? s1a[j] : s1b[j - 4];
            float e0 = kv0 > 0.f ? kv0 + 1.f : __expf(kv0);
            float e1 = kv1 > 0.f ? kv1 + 1.f : __expf(kv1);
            ks0 += e0; ks1 += e1;
            float se = bf_lo(sc0), ce = bf_hi(sc0);
            float so = bf_lo(sc1), co = bf_hi(sc1);
            o0[j] = f2bf(e0 * ce - e1 * se);
            o1[j] = f2bf(e1 * co + e0 * so);
        }
        u32x4 w0, w1;
#pragma unroll
        for (int q = 0; q < 4; ++q) {
            w0[q] = (u32)o0[2 * q] | ((u32)o0[2 * q + 1] << 16);
            w1[q] = (u32)o1[2 * q] | ((u32)o1[2 * q + 1] << 16);
        }
        *(u32x4*)&ks_bf[2 * p][g * 8] = w0;
        *(u32x4*)&ks_bf[2 * p + 1][g * 8] = w1;

#pragma unroll
        for (int j = 0; j < 8; ++j) { vs += b2f((u16)va[j]); }
#pragma unroll
        for (int j = 0; j < 8; ++j) { vs += b2f((u16)vb[j]); }
        *(bf16x8*)&v_bf[dv][g2 * 16] = va;
        *(bf16x8*)&v_bf[dv][g2 * 16 + 8] = vb;
        __syncthreads();

        int kcol = w * 32 + kg * 8;
        bf16x8 af[2], bfv[2];
#pragma unroll
        for (int i = 0; i < 2; ++i) {
            af[i]  = *(const bf16x8*)&ks_bf[i * 16 + fr][kcol];
            bfv[i] = *(const bf16x8*)&v_bf[i * 16 + fr][kcol];
        }
#pragma unroll
        for (int i = 0; i < 2; ++i)
#pragma unroll
            for (int jj = 0; jj < 2; ++jj)
                acc[i][jj] = __builtin_amdgcn_mfma_f32_16x16x32_bf16(af[i], bfv[jj], acc[i][jj], 0, 0, 0);
    }

#pragma unroll
    for (int i = 0; i < 2; ++i)
#pragma unroll
        for (int jj = 0; jj < 2; ++jj)
#pragma unroll
            for (int r = 0; r < 4; ++r) {
                int row = i * 16 + kg * 4 + r;
                int col = jj * 16 + fr;
                red[w * 1024 + row * 32 + col] = acc[i][jj][r];
            }

#pragma unroll
    for (int m = 1; m < 16; m <<= 1) {
        ks0 += __shfl_xor(ks0, m);
        ks1 += __shfl_xor(ks1, m);
    }
    if ((lane & 15) == 0) { redk[2 * p] = ks0; redk[2 * p + 1] = ks1; }
#pragma unroll
    for (int m = 1; m < 8; m <<= 1) vs += __shfl_xor(vs, m);
    if ((lane & 7) == 0) redv[dv] = vs;
    __syncthreads();

    float* pkv = part_kv + ((size_t)bn * 16 + chunk) * 1024;
#pragma unroll
    for (int i = 0; i < 4; ++i) {
        int el = i * 256 + t;
        pkv[el] = red[el] + red[1024 + el] + red[2048 + el] + red[3072 + el];
    }
    if (t < 32) {
        part_ks[((size_t)bn * 16 + chunk) * 32 + t] = redk[t];
        part_vs[((size_t)bn * 16 + chunk) * 32 + t] = redv[t];
    }
}

// kv_final: sum 16 chunk partials -> kvT bf16 [e][d]; kmean/vmean
__global__ __launch_bounds__(256) void kv_final(const float* __restrict__ part_kv, const float* __restrict__ part_ks,
                                                const float* __restrict__ part_vs, u16* __restrict__ kvT_bf,
                                                float* __restrict__ kmean, float* __restrict__ vmean) {
    int bn = blockIdx.x;
    int t = threadIdx.x;
    const float* p = part_kv + (size_t)bn * 16 * 1024;
    const float s2c = SCALE_F / (float)N_TOK;
#pragma unroll
    for (int i = 0; i < 4; ++i) {
        int sl = t + i * 256;          // sl = d*32 + e
        float s = 0;
#pragma unroll
        for (int c = 0; c < 16; ++c) s += p[(size_t)c * 1024 + sl];
        float val = s * s2c;
        int d = sl >> 5, e = sl & 31;
        kvT_bf[(size_t)bn * 1024 + e * 32 + d] = f2bf(val);
    }
    if (t < 32) {
        float s = 0, sv = 0;
        for (int c = 0; c < 16; ++c) {
            s  += part_ks[((size_t)bn * 16 + c) * 32 + t];
            sv += part_vs[((size_t)bn * 16 + c) * 32 + t];
        }
        kmean[bn * 32 + t] = s * (1.f / (float)N_TOK);
        vmean[bn * 32 + t] = sv * (1.f / (float)N_TOK);
    }
}

// ---------------- attention epilogue, MFMA matvec -> resnT[b][l][c] bf16 ----------------
__global__ __launch_bounds__(256) void attn_epilogue(const u16* __restrict__ qkvo, const u32* __restrict__ scT,
                                                     const u16* __restrict__ kvT_bf, const float* __restrict__ kmean,
                                                     const float* __restrict__ vmean, const u16* __restrict__ lepe,
                                                     u16* __restrict__ resnT) {
    int lt = blockIdx.x, bn = blockIdx.y;
    int b = bn >> 3, n = bn & 7;
    const u16* qp = qkvo + ((size_t)b * 1024 + n * HD) * N_TOK;
    const u16* op = qkvo + ((size_t)b * 1024 + 768 + n * HD) * N_TOK;
    const u16* lp = lepe + ((size_t)b * C_DIM + n * HD) * N_TOK;

    __shared__ u16 kvb[32 * 40];            // kv^T [e][d] bf16, stride 40
    __shared__ float kml[32], vml[32];
    __shared__ u16 Atile[4][64 * 40];       // per-wave q' bf16 [tok][d], stride 40
    __shared__ float Rtile[4][64 * 36];     // per-wave res f32 [tok][e], stride 36

    int t = threadIdx.x;
    int w = t >> 6, lane = t & 63;

    if (t < 128) {
        int e = t >> 2, d0 = (t & 3) * 8;
        *(uint4*)(kvb + e * 40 + d0) = *(const uint4*)(kvT_bf + (size_t)bn * 1024 + e * 32 + d0);
    }
    if (t < 32) { kml[t] = kmean[bn * 32 + t]; vml[t] = vmean[bn * 32 + t]; }
    __syncthreads();

    int token = lt * 256 + w * 64 + lane;

    float qv[32];
    float z = 0.f;
#pragma unroll
    for (int d = 0; d < 32; ++d) {
        float x_ = b2f(qp[(size_t)d * N_TOK + token]);
        float e_ = x_ > 0.f ? x_ + 1.f : __expf(x_);
        qv[d] = e_;
        z += e_ * kml[d];
    }
    z *= SCALE_F;
#pragma unroll
    for (int p = 0; p < 16; ++p) {
        u32 sc0 = scT[(size_t)(2 * p) * N_TOK + token];
        u32 sc1 = scT[(size_t)(2 * p + 1) * N_TOK + token];
        float se = bf_lo(sc0), ce = bf_hi(sc0);
        float so = bf_lo(sc1), co = bf_hi(sc1);
        float a = qv[2 * p], bb = qv[2 * p + 1];
        qv[2 * p]     = a * ce - bb * se;
        qv[2 * p + 1] = bb * co + a * so;
    }
    float mult = 1.f + 1.f / (z + 1e-6f);

    u16* Aw = Atile[w];
#pragma unroll
    for (int j4 = 0; j4 < 4; ++j4) {
        uint4 u;
        u.x = (u32)f2bf(qv[8 * j4 + 0]) | ((u32)f2bf(qv[8 * j4 + 1]) << 16);
        u.y = (u32)f2bf(qv[8 * j4 + 2]) | ((u32)f2bf(qv[8 * j4 + 3]) << 16);
        u.z = (u32)f2bf(qv[8 * j4 + 4]) | ((u32)f2bf(qv[8 * j4 + 5]) << 16);
        u.w = (u32)f2bf(qv[8 * j4 + 6]) | ((u32)f2bf(qv[8 * j4 + 7]) << 16);
        *(uint4*)(Aw + lane * 40 + j4 * 8) = u;
    }
    __syncthreads();

    int fr = lane & 15, kg = lane >> 4;
    bf16x8 af[4], bfr[2];
#pragma unroll
    for (int i = 0; i < 4; ++i)
        af[i] = *(const bf16x8*)(Aw + (i * 16 + fr) * 40 + kg * 8);
#pragma unroll
    for (int jj = 0; jj < 2; ++jj)
        bfr[jj] = *(const bf16x8*)(kvb + (jj * 16 + fr) * 40 + kg * 8);

    float* Rw = Rtile[w];
    f32x4 zero = {0.f, 0.f, 0.f, 0.f};
#pragma unroll
    for (int i = 0; i < 4; ++i)
#pragma unroll
        for (int jj = 0; jj < 2; ++jj) {
            f32x4 acc = __builtin_amdgcn_mfma_f32_16x16x32_bf16(af[i], bfr[jj], zero, 0, 0, 0);
#pragma unroll
            for (int r = 0; r < 4; ++r)
                Rw[(i * 16 + kg * 4 + r) * 36 + jj * 16 + fr] = acc[r];
        }
    __syncthreads();

    float res[32];
#pragma unroll
    for (int j = 0; j < 8; ++j) {
        f32x4 vr = *(const f32x4*)(Rw + lane * 36 + j * 4);
        res[4 * j] = vr[0]; res[4 * j + 1] = vr[1]; res[4 * j + 2] = vr[2]; res[4 * j + 3] = vr[3];
    }

    u16* dst0 = resnT + ((size_t)b * N_TOK + token) * C_DIM + n * HD;
#pragma unroll
    for (int g = 0; g < 4; ++g) {
        float vv[8];
#pragma unroll
        for (int e2 = 0; e2 < 8; ++e2) {
            int ee = g * 8 + e2;
            float lx = b2f(lp[(size_t)ee * N_TOK + token]);
            float ov = b2f(op[(size_t)ee * N_TOK + token]);
            float rx = res[ee] * mult - z * vml[ee];
            vv[e2] = (rx + lx) * ov;
        }
        uint4 u;
        u.x = (u32)f2bf(vv[0]) | ((u32)f2bf(vv[1]) << 16);
        u.y = (u32)f2bf(vv[2]) | ((u32)f2bf(vv[3]) << 16);
        u.z = (u32)f2bf(vv[4]) | ((u32)f2bf(vv[5]) << 16);
        u.w = (u32)f2bf(vv[6]) | ((u32)f2bf(vv[7]) << 16);
        ((uint4*)(dst0 + g * 8))[0] = u;
    }
}

extern "C" void kernel_launch(void* const* d_in, const int* in_sizes, int n_in,
                              void* d_out, int out_size, void* d_ws, size_t ws_size,
                              hipStream_t stream) {
    const float* x      = (const float*)d_in[0];
    const float* sinp   = (const float*)d_in[1];
    const float* cosp   = (const float*)d_in[2];
    const float* w_qkvo = (const float*)d_in[3];
    const float* b_qkvo = (const float*)d_in[4];
    const float* w_lepe = (const float*)d_in[5];
    const float* b_lepe = (const float*)d_in[6];
    const float* w_proj = (const float*)d_in[7];
    const float* b_proj = (const float*)d_in[8];

    char* ws = (char*)d_ws;
    size_t off = 0;
    auto alloc = [&](size_t bytes) { size_t o = off; off = (off + bytes + 255) & ~(size_t)255; return o; };
    u16*   wbf     = (u16*)(ws + alloc((size_t)1024 * 256 * 2));
    u16*   wpbf    = (u16*)(ws + alloc((size_t)256 * 256 * 2));
    u16*   xT      = (u16*)(ws + alloc((size_t)8 * 4096 * 256 * 2));
    u16*   qkvo    = (u16*)(ws + alloc((size_t)8 * 1024 * 4096 * 2));
    u16*   lepe    = (u16*)(ws + alloc((size_t)8 * 256 * 4096 * 2));
    u16*   resnT   = (u16*)(ws + alloc((size_t)8 * 4096 * 256 * 2));
    float* part_kv = (float*)(ws + alloc((size_t)64 * 16 * 1024 * 4));
    float* part_ks = (float*)(ws + alloc((size_t)64 * 16 * 32 * 4));
    float* part_vs = (float*)(ws + alloc((size_t)64 * 16 * 32 * 4));
    u16*   kvT_bf  = (u16*)(ws + alloc((size_t)64 * 1024 * 2));
    float* kmean   = (float*)(ws + alloc((size_t)64 * 32 * 4));
    float* vmean   = (float*)(ws + alloc((size_t)64 * 32 * 4));
    u32*   scT     = (u32*)(ws + alloc((size_t)32 * 4096 * 4));
    if (off > ws_size) return;  // insufficient workspace -> loud validation failure

    conv_w<<<dim3(1024), dim3(256), 0, stream>>>(w_qkvo, w_proj, wbf, wpbf);
    make_sc<<<dim3(64), dim3(256), 0, stream>>>(sinp, cosp, scT);
    transpose_x<<<dim3(128, 8, 8), dim3(256), 0, stream>>>(x, xT);
    gemm_bt<u16><<<dim3(32, 8, 8), dim3(256), 0, stream>>>(wbf, xT, b_qkvo, qkvo, 1024, 4096, 256);
    lepe_conv<<<dim3(256, 8), dim3(256), 0, stream>>>(qkvo, w_lepe, b_lepe, lepe);
    kv_reduce<<<dim3(16, 64), dim3(256), 0, stream>>>(qkvo, scT, part_kv, part_ks, part_vs);
    kv_final<<<dim3(64), dim3(256), 0, stream>>>(part_kv, part_ks, part_vs, kvT_bf, kmean, vmean);
    attn_epilogue<<<dim3(16, 64), dim3(256), 0, stream>>>(qkvo, scT, kvT_bf, kmean, vmean, lepe, resnT);
    gemm_bt<float><<<dim3(32, 2, 8), dim3(256), 0, stream>>>(wpbf, resnT, b_proj, (float*)d_out, 256, 4096, 256);
}